// Round 1
// baseline (641.167 us; speedup 1.0000x reference)
//
#include <hip/hip_runtime.h>
#include <hip/hip_bf16.h>

typedef __bf16 bf16x8 __attribute__((ext_vector_type(8)));
typedef float f32x4 __attribute__((ext_vector_type(4)));

#define T_TOK 4096
#define H_DIM 1024
#define F_DIM 2048
#define NEXP 8
#define TOTROWS 8192   // T_TOK * TOP_K, always exact (top-2 distinct experts)
#define MAXTILES 80

__device__ inline unsigned short f2b(float f) {
    unsigned int u = __float_as_uint(f);
    unsigned int r = (u + 0x7fffu + ((u >> 16) & 1u)) >> 16;
    return (unsigned short)r;
}

// async global->LDS, 16B per lane. LDS dst = wave-uniform base + lane*16.
__device__ inline void gload16(const void* g, void* l) {
    __builtin_amdgcn_global_load_lds(
        (const __attribute__((address_space(1))) unsigned int*)g,
        (__attribute__((address_space(3))) unsigned int*)l,
        16, 0, 0);
}

// ---------------- router: logits -> softmax -> top2 -> renorm (4 tokens/block, no atomics) ----
__global__ __launch_bounds__(256) void router_kernel(const float* __restrict__ x,
                                                     const float* __restrict__ gw,
                                                     int* __restrict__ sel, float* __restrict__ selw) {
    int t = blockIdx.x * 4 + (threadIdx.x >> 6);
    int lane = threadIdx.x & 63;
    float acc[8] = {0.f,0.f,0.f,0.f,0.f,0.f,0.f,0.f};
    const float* xr = x + (size_t)t * H_DIM;
    for (int h = lane; h < H_DIM; h += 64) {
        float xv = xr[h];
        const float4* g = (const float4*)(gw + h * 8);
        float4 g0 = g[0], g1 = g[1];
        acc[0] += xv * g0.x; acc[1] += xv * g0.y; acc[2] += xv * g0.z; acc[3] += xv * g0.w;
        acc[4] += xv * g1.x; acc[5] += xv * g1.y; acc[6] += xv * g1.z; acc[7] += xv * g1.w;
    }
#pragma unroll
    for (int off = 32; off >= 1; off >>= 1)
#pragma unroll
        for (int e = 0; e < 8; ++e)
            acc[e] += __shfl_down(acc[e], off);
    if (lane == 0) {
        float mx = acc[0];
#pragma unroll
        for (int e = 1; e < 8; ++e) mx = fmaxf(mx, acc[e]);
        float p[8]; float s = 0.f;
#pragma unroll
        for (int e = 0; e < 8; ++e) { p[e] = expf(acc[e] - mx); s += p[e]; }
        float inv_s = 1.f / s;
#pragma unroll
        for (int e = 0; e < 8; ++e) p[e] *= inv_s;
        int e1 = 0; float p1 = p[0];
#pragma unroll
        for (int e = 1; e < 8; ++e) if (p[e] > p1) { p1 = p[e]; e1 = e; }
        int e2 = -1; float p2 = -1.f;
#pragma unroll
        for (int e = 0; e < 8; ++e) { if (e == e1) continue; if (p[e] > p2) { p2 = p[e]; e2 = e; } }
        float inv = 1.f / (p1 + p2);
        sel[t * 2 + 0] = e1; sel[t * 2 + 1] = e2;
        selw[t * 2 + 0] = p1 * inv; selw[t * 2 + 1] = p2 * inv;
    }
}

// ---------------- scan: histogram sel -> cnt/off/fill/tile table (1 block) ----------------
__global__ __launch_bounds__(256) void scan_kernel(const int* __restrict__ sel,
                                                   int* __restrict__ cnt, int* __restrict__ off,
                                                   int* __restrict__ fill,
                                                   int* __restrict__ tileExp, int* __restrict__ tileM0) {
    __shared__ int h[NEXP];
    int tid = threadIdx.x;
    if (tid < NEXP) h[tid] = 0;
    __syncthreads();
    for (int i = tid; i < TOTROWS; i += 256) atomicAdd(&h[sel[i]], 1);
    __syncthreads();
    if (tid == 0) {
        int o = 0;
        for (int e = 0; e < NEXP; ++e) { cnt[e] = h[e]; off[e] = o; o += h[e]; fill[e] = 0; }
        int nt = 0;
        for (int e = 0; e < NEXP; ++e)
            for (int m0 = 0; m0 < h[e]; m0 += 128) { tileExp[nt] = e; tileM0[nt] = m0; nt++; }
        for (int i = nt; i < MAXTILES; ++i) { tileExp[i] = -1; tileM0[i] = 0; }
    }
}

// ---------------- fused scatter+gather: slots + copy x row (bf16) to both expert rows --------
__global__ __launch_bounds__(256) void scatgath_kernel(const int* __restrict__ sel,
                                                       const float* __restrict__ selw,
                                                       const int* __restrict__ off,
                                                       int* __restrict__ fill,
                                                       float* __restrict__ rowWgt,
                                                       int* __restrict__ tokRow,
                                                       const float* __restrict__ x,
                                                       unsigned short* __restrict__ Xg) {
    __shared__ int rs[2];
    int t = blockIdx.x;
    int tid = threadIdx.x;
    if (tid == 0) {
#pragma unroll
        for (int k = 0; k < 2; ++k) {
            int e = sel[t * 2 + k];
            int slot = atomicAdd(&fill[e], 1);
            int r = off[e] + slot;
            rowWgt[r] = selw[t * 2 + k];
            tokRow[t * 2 + k] = r;
            rs[k] = r;
        }
    }
    __syncthreads();
    int r1 = rs[0], r2 = rs[1];
    float4 v = ((const float4*)(x + (size_t)t * H_DIM))[tid];
    ushort4 o;
    o.x = f2b(v.x); o.y = f2b(v.y); o.z = f2b(v.z); o.w = f2b(v.w);
    ((ushort4*)(Xg + (size_t)r1 * H_DIM))[tid] = o;
    ((ushort4*)(Xg + (size_t)r2 * H_DIM))[tid] = o;
}

// ---------------- fused transpose+cvt for all 3 weight tensors ----------------
__global__ __launch_bounds__(256) void transpose_cvt_kernel(
        const float* __restrict__ w_up, const float* __restrict__ w_gate,
        const float* __restrict__ w_down,
        unsigned short* __restrict__ wTu, unsigned short* __restrict__ wTg,
        unsigned short* __restrict__ wTd) {
    __shared__ unsigned short lt[64 * 68];
    int z = blockIdx.z;
    int e = blockIdx.y;
    const float* src; unsigned short* dst; int R, C, tr, tc;
    if (z == 0)      { src = w_up;   dst = wTu; R = H_DIM; C = F_DIM; }
    else if (z == 1) { src = w_gate; dst = wTg; R = H_DIM; C = F_DIM; }
    else             { src = w_down; dst = wTd; R = F_DIM; C = H_DIM; }
    if (R == H_DIM) { tc = blockIdx.x & 31; tr = blockIdx.x >> 5; }
    else            { tc = blockIdx.x & 15; tr = blockIdx.x >> 4; }
    const float* s = src + (size_t)e * H_DIM * F_DIM;
    unsigned short* d = dst + (size_t)e * H_DIM * F_DIM;
    int r0 = tr * 64, c0 = tc * 64;
    int tid = threadIdx.x;
    int fc = tid & 15, row = tid >> 4;
#pragma unroll
    for (int i = 0; i < 4; ++i) {
        int r = row + i * 16;
        float4 v = *(const float4*)(s + (size_t)(r0 + r) * C + c0 + fc * 4);
        lt[(fc * 4 + 0) * 68 + r] = f2b(v.x);
        lt[(fc * 4 + 1) * 68 + r] = f2b(v.y);
        lt[(fc * 4 + 2) * 68 + r] = f2b(v.z);
        lt[(fc * 4 + 3) * 68 + r] = f2b(v.w);
    }
    __syncthreads();
    int ch = tid & 7, cc = tid >> 3;
#pragma unroll
    for (int i = 0; i < 2; ++i) {
        int c = cc + i * 32;
        uint2 lo = *(const uint2*)&lt[c * 68 + ch * 8];
        uint2 hi = *(const uint2*)&lt[c * 68 + ch * 8 + 4];
        uint4 o = make_uint4(lo.x, lo.y, hi.x, hi.y);
        *(uint4*)(d + (size_t)(c0 + c) * R + r0 + ch * 8) = o;
    }
}

// ---------------- fused up/gate GEMM, BK=32, double-buffered prefetch, 1 barrier/step -------
// LDS layout per tile: k-chunk-major [4 qchunks][128 rows][16B]. slot p (16B units):
//   q = p>>7, r = p&127; src elem off = r*LD + q*8. Fragment ds_read_b128 at
//   quad*1024 + row*8 (ushort idx) -> 256B-contiguous per 16 lanes: conflict-free, no XOR.
__global__ __launch_bounds__(256, 2) void gemm_upgate_kernel(
        const unsigned short* __restrict__ Xg,
        const unsigned short* __restrict__ wTu,   // [E][F][H] (k-major)
        const unsigned short* __restrict__ wTg,
        unsigned short* __restrict__ inner,       // [TOTROWS][F]
        const int* __restrict__ tileExp, const int* __restrict__ tileM0,
        const int* __restrict__ off, const int* __restrict__ cnt) {
    __shared__ __align__(16) unsigned short la[2][4096];   // 8KB x2
    __shared__ __align__(16) unsigned short lbu[2][4096];
    __shared__ __align__(16) unsigned short lbg[2][4096];  // total 48KB -> 2 blocks/CU
    int bt = blockIdx.y;
    int e = tileExp[bt];
    if (e < 0) return;
    int m0 = tileM0[bt];
    int r0 = off[e] + m0;
    int valid = cnt[e] - m0;
    int f0 = blockIdx.x * 128;
    const unsigned short* aB = Xg + (size_t)r0 * H_DIM;
    const unsigned short* bu = wTu + (size_t)e * F_DIM * H_DIM + (size_t)f0 * H_DIM;
    const unsigned short* bg = wTg + (size_t)e * F_DIM * H_DIM + (size_t)f0 * H_DIM;
    int tid = threadIdx.x;
    int lane = tid & 63, wid = tid >> 6;
    int wm = wid >> 1, wn = wid & 1;
    int l16 = lane & 15, quad = lane >> 4;

    // staging: 512 slots of 16B per tile; 2 iters x 256 threads; wave-uniform LDS base.
    int sOff[2], lb_[2];
#pragma unroll
    for (int it = 0; it < 2; ++it) {
        int p = it * 256 + tid;
        sOff[it] = (p & 127) * H_DIM + ((p >> 7) << 3);
        lb_[it] = it * 2048 + wid * 512;   // ushort idx of wave-uniform base
    }
    f32x4 accU[4][4], accG[4][4];
#pragma unroll
    for (int i = 0; i < 4; ++i)
#pragma unroll
        for (int j = 0; j < 4; ++j) { accU[i][j] = (f32x4)0.f; accG[i][j] = (f32x4)0.f; }

    int aRd = quad * 1024 + (wm * 64 + l16) * 8;
    int bRd = quad * 1024 + (wn * 64 + l16) * 8;

    // prologue: stage k-tile 0 into buf 0
#pragma unroll
    for (int it = 0; it < 2; ++it) {
        gload16(aB + sOff[it], &la[0][lb_[it]]);   // tail rows overread into ws (discarded)
        gload16(bu + sOff[it], &lbu[0][lb_[it]]);
        gload16(bg + sOff[it], &lbg[0][lb_[it]]);
    }
    __syncthreads();   // implicit vmcnt(0) drain: buf0 ready

    int cur = 0;
    for (int k0 = 32; k0 <= H_DIM; k0 += 32) {   // compute tile (k0-32), prefetch tile k0
        int nxt = cur ^ 1;
        if (k0 < H_DIM) {
#pragma unroll
            for (int it = 0; it < 2; ++it) {
                gload16(aB + sOff[it] + k0, &la[nxt][lb_[it]]);
                gload16(bu + sOff[it] + k0, &lbu[nxt][lb_[it]]);
                gload16(bg + sOff[it] + k0, &lbg[nxt][lb_[it]]);
            }
        }
        bf16x8 af[4], bfu[4], bfg[4];
#pragma unroll
        for (int i = 0; i < 4; ++i) af[i] = *(const bf16x8*)&la[cur][aRd + i * 128];
#pragma unroll
        for (int j = 0; j < 4; ++j) {
            bfu[j] = *(const bf16x8*)&lbu[cur][bRd + j * 128];
            bfg[j] = *(const bf16x8*)&lbg[cur][bRd + j * 128];
        }
#pragma unroll
        for (int i = 0; i < 4; ++i)
#pragma unroll
            for (int j = 0; j < 4; ++j) {
                accU[i][j] = __builtin_amdgcn_mfma_f32_16x16x32_bf16(af[i], bfu[j], accU[i][j], 0, 0, 0);
                accG[i][j] = __builtin_amdgcn_mfma_f32_16x16x32_bf16(af[i], bfg[j], accG[i][j], 0, 0, 0);
            }
        __syncthreads();   // drains prefetch vmcnt + this step's lgkmcnt; one barrier/step
        cur = nxt;
    }
#pragma unroll
    for (int i = 0; i < 4; ++i) {
#pragma unroll
        for (int rr = 0; rr < 4; ++rr) {
            int ml = wm * 64 + i * 16 + quad * 4 + rr;
            if (ml >= valid) continue;
            size_t base = (size_t)(r0 + ml) * F_DIM + f0;
#pragma unroll
            for (int j = 0; j < 4; ++j) {
                float u = accU[i][j][rr];
                float g = accG[i][j][rr];
                // silu(up)*gate with fast exp + v_rcp (bf16 output: approx ok)
                float v = u * __builtin_amdgcn_rcpf(1.f + __expf(-u)) * g;
                inner[base + wn * 64 + j * 16 + l16] = f2b(v);
            }
        }
    }
}

// ---------------- down GEMM, BK=64, double-buffered prefetch, 1 barrier/step ----------------
__global__ __launch_bounds__(256, 2) void gemm_down_kernel(
        const unsigned short* __restrict__ inner,  // [TOTROWS][F]
        const unsigned short* __restrict__ wTd,    // [E][H][F] (k-major)
        float* __restrict__ part,                  // [TOTROWS][H]
        const int* __restrict__ tileExp, const int* __restrict__ tileM0,
        const int* __restrict__ off, const int* __restrict__ cnt,
        const float* __restrict__ rowWgt) {
    __shared__ __align__(16) unsigned short la[2][8192];   // 16KB x2
    __shared__ __align__(16) unsigned short lb[2][8192];   // total 64KB -> 2 blocks/CU
    int bt = blockIdx.y;
    int e = tileExp[bt];
    if (e < 0) return;
    int m0 = tileM0[bt];
    int r0 = off[e] + m0;
    int valid = cnt[e] - m0;
    int h0 = blockIdx.x * 128;
    const unsigned short* aB = inner + (size_t)r0 * F_DIM;
    const unsigned short* bp = wTd + (size_t)e * H_DIM * F_DIM + (size_t)h0 * F_DIM;
    int tid = threadIdx.x;
    int lane = tid & 63, wid = tid >> 6;
    int wm = wid >> 1, wn = wid & 1;
    int l16 = lane & 15, quad = lane >> 4;

    // 1024 slots of 16B per tile (BK=64: 8 qchunks x 128 rows); 4 iters x 256 threads.
    int sOff[4], lb_[4];
#pragma unroll
    for (int it = 0; it < 4; ++it) {
        int p = it * 256 + tid;
        sOff[it] = (p & 127) * F_DIM + ((p >> 7) << 3);
        lb_[it] = it * 2048 + wid * 512;
    }
    f32x4 acc[4][4];
#pragma unroll
    for (int i = 0; i < 4; ++i)
#pragma unroll
        for (int j = 0; j < 4; ++j) acc[i][j] = (f32x4)0.f;

    int aRd = (wm * 64 + l16) * 8;
    int bRd = (wn * 64 + l16) * 8;

    // prologue: stage k-tile 0 into buf 0
#pragma unroll
    for (int it = 0; it < 4; ++it) {
        gload16(aB + sOff[it], &la[0][lb_[it]]);   // tail rows overread into ws pad
        gload16(bp + sOff[it], &lb[0][lb_[it]]);
    }
    __syncthreads();

    int cur = 0;
    for (int k0 = 64; k0 <= F_DIM; k0 += 64) {   // compute tile (k0-64), prefetch tile k0
        int nxt = cur ^ 1;
        if (k0 < F_DIM) {
#pragma unroll
            for (int it = 0; it < 4; ++it) {
                gload16(aB + sOff[it] + k0, &la[nxt][lb_[it]]);
                gload16(bp + sOff[it] + k0, &lb[nxt][lb_[it]]);
            }
        }
#pragma unroll
        for (int h = 0; h < 2; ++h) {
            bf16x8 af[4], bf[4];
#pragma unroll
            for (int i = 0; i < 4; ++i)
                af[i] = *(const bf16x8*)&la[cur][(h * 4 + quad) * 1024 + aRd + i * 128];
#pragma unroll
            for (int j = 0; j < 4; ++j)
                bf[j] = *(const bf16x8*)&lb[cur][(h * 4 + quad) * 1024 + bRd + j * 128];
#pragma unroll
            for (int i = 0; i < 4; ++i)
#pragma unroll
                for (int j = 0; j < 4; ++j)
                    acc[i][j] = __builtin_amdgcn_mfma_f32_16x16x32_bf16(af[i], bf[j], acc[i][j], 0, 0, 0);
        }
        __syncthreads();
        cur = nxt;
    }
#pragma unroll
    for (int i = 0; i < 4; ++i) {
#pragma unroll
        for (int rr = 0; rr < 4; ++rr) {
            int ml = wm * 64 + i * 16 + quad * 4 + rr;
            if (ml >= valid) continue;
            int gr = r0 + ml;
            float w = rowWgt[gr];
            float* orow = part + (size_t)gr * H_DIM + h0;
#pragma unroll
            for (int j = 0; j < 4; ++j)
                orow[wn * 64 + j * 16 + l16] = w * acc[i][j][rr];
        }
    }
}

// ---------------- combine: out[t] = part[r1] + part[r2] ----------------
__global__ __launch_bounds__(256) void combine_kernel(const float* __restrict__ part,
                                                      const int* __restrict__ tokRow,
                                                      float* __restrict__ out) {
    int t = blockIdx.x;
    int r1 = tokRow[t * 2 + 0], r2 = tokRow[t * 2 + 1];
    int i = threadIdx.x;
    float4 a = ((const float4*)(part + (size_t)r1 * H_DIM))[i];
    float4 b = ((const float4*)(part + (size_t)r2 * H_DIM))[i];
    float4 o;
    o.x = a.x + b.x; o.y = a.y + b.y; o.z = a.z + b.z; o.w = a.w + b.w;
    ((float4*)(out + (size_t)t * H_DIM))[i] = o;
}

extern "C" void kernel_launch(void* const* d_in, const int* in_sizes, int n_in,
                              void* d_out, int out_size, void* d_ws, size_t ws_size,
                              hipStream_t stream) {
    const float* x      = (const float*)d_in[0];
    const float* gw     = (const float*)d_in[1];
    const float* w_up   = (const float*)d_in[2];
    const float* w_gate = (const float*)d_in[3];
    const float* w_down = (const float*)d_in[4];
    float* out = (float*)d_out;

    char* ws = (char*)d_ws;
    size_t o = 0;
    unsigned short* wTu = (unsigned short*)(ws + o); o += (size_t)NEXP * F_DIM * H_DIM * 2;
    unsigned short* wTg = (unsigned short*)(ws + o); o += (size_t)NEXP * F_DIM * H_DIM * 2;
    unsigned short* wTd = (unsigned short*)(ws + o); o += (size_t)NEXP * H_DIM * F_DIM * 2;
    unsigned short* Xg  = (unsigned short*)(ws + o); o += (size_t)TOTROWS * H_DIM * 2;
    unsigned short* inner = (unsigned short*)(ws + o); o += (size_t)TOTROWS * F_DIM * 2;
    o += 1024 * 1024;  // pad: tail-row overreads past inner (up to ~520KB) stay in ws
    float* rowWgt = (float*)(ws + o); o += TOTROWS * 4;
    int*   tokRow = (int*)(ws + o);   o += T_TOK * 2 * 4;
    int*   sel    = (int*)(ws + o);   o += T_TOK * 2 * 4;
    float* selw   = (float*)(ws + o); o += T_TOK * 2 * 4;
    int*   cnt    = (int*)(ws + o);   o += 8 * 4;
    int*   fill   = (int*)(ws + o);   o += 8 * 4;
    int*   off_   = (int*)(ws + o);   o += 8 * 4;
    int*   tileExp = (int*)(ws + o);  o += MAXTILES * 4;
    int*   tileM0  = (int*)(ws + o);  o += MAXTILES * 4;
    // part[TOTROWS][H] fp32 aliases wTu+wTg (dead after gemm_upgate; stream-serial)
    float* part = (float*)wTu;

    router_kernel<<<T_TOK / 4, 256, 0, stream>>>(x, gw, sel, selw);
    scan_kernel<<<1, 256, 0, stream>>>(sel, cnt, off_, fill, tileExp, tileM0);
    scatgath_kernel<<<T_TOK, 256, 0, stream>>>(sel, selw, off_, fill, rowWgt, tokRow, x, Xg);
    transpose_cvt_kernel<<<dim3(512, NEXP, 3), 256, 0, stream>>>(w_up, w_gate, w_down, wTu, wTg, wTd);
    gemm_upgate_kernel<<<dim3(F_DIM / 128, 72), 256, 0, stream>>>(Xg, wTu, wTg, inner, tileExp, tileM0, off_, cnt);
    gemm_down_kernel<<<dim3(H_DIM / 128, 72), 256, 0, stream>>>(inner, wTd, part, tileExp, tileM0, off_, cnt, rowWgt);
    combine_kernel<<<T_TOK, 256, 0, stream>>>(part, tokRow, out);
}

// Round 2
// 574.780 us; speedup vs baseline: 1.1155x; 1.1155x over previous
//
#include <hip/hip_runtime.h>
#include <hip/hip_bf16.h>

typedef __bf16 bf16x8 __attribute__((ext_vector_type(8)));
typedef float f32x4 __attribute__((ext_vector_type(4)));

#define T_TOK 4096
#define H_DIM 1024
#define F_DIM 2048
#define NEXP 8
#define TOTROWS 8192   // T_TOK * TOP_K, always exact (top-2 distinct experts)
#define MAXTILES 80

__device__ inline unsigned short f2b(float f) {
    unsigned int u = __float_as_uint(f);
    unsigned int r = (u + 0x7fffu + ((u >> 16) & 1u)) >> 16;
    return (unsigned short)r;
}

// async global->LDS, 16B per lane. LDS dst = wave-uniform base + lane*16.
__device__ inline void gload16(const void* g, void* l) {
    __builtin_amdgcn_global_load_lds(
        (const __attribute__((address_space(1))) unsigned int*)g,
        (__attribute__((address_space(3))) unsigned int*)l,
        16, 0, 0);
}

// ---------------- router: logits -> softmax -> top2 -> renorm (4 tokens/block, no atomics) ----
__global__ __launch_bounds__(256) void router_kernel(const float* __restrict__ x,
                                                     const float* __restrict__ gw,
                                                     int* __restrict__ sel, float* __restrict__ selw) {
    int t = blockIdx.x * 4 + (threadIdx.x >> 6);
    int lane = threadIdx.x & 63;
    float acc[8] = {0.f,0.f,0.f,0.f,0.f,0.f,0.f,0.f};
    const float* xr = x + (size_t)t * H_DIM;
    for (int h = lane; h < H_DIM; h += 64) {
        float xv = xr[h];
        const float4* g = (const float4*)(gw + h * 8);
        float4 g0 = g[0], g1 = g[1];
        acc[0] += xv * g0.x; acc[1] += xv * g0.y; acc[2] += xv * g0.z; acc[3] += xv * g0.w;
        acc[4] += xv * g1.x; acc[5] += xv * g1.y; acc[6] += xv * g1.z; acc[7] += xv * g1.w;
    }
#pragma unroll
    for (int off = 32; off >= 1; off >>= 1)
#pragma unroll
        for (int e = 0; e < 8; ++e)
            acc[e] += __shfl_down(acc[e], off);
    if (lane == 0) {
        float mx = acc[0];
#pragma unroll
        for (int e = 1; e < 8; ++e) mx = fmaxf(mx, acc[e]);
        float p[8]; float s = 0.f;
#pragma unroll
        for (int e = 0; e < 8; ++e) { p[e] = expf(acc[e] - mx); s += p[e]; }
        float inv_s = 1.f / s;
#pragma unroll
        for (int e = 0; e < 8; ++e) p[e] *= inv_s;
        int e1 = 0; float p1 = p[0];
#pragma unroll
        for (int e = 1; e < 8; ++e) if (p[e] > p1) { p1 = p[e]; e1 = e; }
        int e2 = -1; float p2 = -1.f;
#pragma unroll
        for (int e = 0; e < 8; ++e) { if (e == e1) continue; if (p[e] > p2) { p2 = p[e]; e2 = e; } }
        float inv = 1.f / (p1 + p2);
        sel[t * 2 + 0] = e1; sel[t * 2 + 1] = e2;
        selw[t * 2 + 0] = p1 * inv; selw[t * 2 + 1] = p2 * inv;
    }
}

// ---------------- scan: histogram sel -> cnt/off/fill/tile table (1 block) ----------------
__global__ __launch_bounds__(256) void scan_kernel(const int* __restrict__ sel,
                                                   int* __restrict__ cnt, int* __restrict__ off,
                                                   int* __restrict__ fill,
                                                   int* __restrict__ tileExp, int* __restrict__ tileM0) {
    __shared__ int h[NEXP];
    int tid = threadIdx.x;
    if (tid < NEXP) h[tid] = 0;
    __syncthreads();
    for (int i = tid; i < TOTROWS; i += 256) atomicAdd(&h[sel[i]], 1);
    __syncthreads();
    if (tid == 0) {
        int o = 0;
        for (int e = 0; e < NEXP; ++e) { cnt[e] = h[e]; off[e] = o; o += h[e]; fill[e] = 0; }
        int nt = 0;
        for (int e = 0; e < NEXP; ++e)
            for (int m0 = 0; m0 < h[e]; m0 += 128) { tileExp[nt] = e; tileM0[nt] = m0; nt++; }
        for (int i = nt; i < MAXTILES; ++i) { tileExp[i] = -1; tileM0[i] = 0; }
    }
}

// ---------------- fused scatter+gather: slots + copy x row (bf16) to both expert rows --------
__global__ __launch_bounds__(256) void scatgath_kernel(const int* __restrict__ sel,
                                                       const float* __restrict__ selw,
                                                       const int* __restrict__ off,
                                                       int* __restrict__ fill,
                                                       float* __restrict__ rowWgt,
                                                       int* __restrict__ tokRow,
                                                       const float* __restrict__ x,
                                                       unsigned short* __restrict__ Xg) {
    __shared__ int rs[2];
    int t = blockIdx.x;
    int tid = threadIdx.x;
    if (tid == 0) {
#pragma unroll
        for (int k = 0; k < 2; ++k) {
            int e = sel[t * 2 + k];
            int slot = atomicAdd(&fill[e], 1);
            int r = off[e] + slot;
            rowWgt[r] = selw[t * 2 + k];
            tokRow[t * 2 + k] = r;
            rs[k] = r;
        }
    }
    __syncthreads();
    int r1 = rs[0], r2 = rs[1];
    float4 v = ((const float4*)(x + (size_t)t * H_DIM))[tid];
    ushort4 o;
    o.x = f2b(v.x); o.y = f2b(v.y); o.z = f2b(v.z); o.w = f2b(v.w);
    ((ushort4*)(Xg + (size_t)r1 * H_DIM))[tid] = o;
    ((ushort4*)(Xg + (size_t)r2 * H_DIM))[tid] = o;
}

// ---------------- fused transpose+cvt for all 3 weight tensors ----------------
__global__ __launch_bounds__(256) void transpose_cvt_kernel(
        const float* __restrict__ w_up, const float* __restrict__ w_gate,
        const float* __restrict__ w_down,
        unsigned short* __restrict__ wTu, unsigned short* __restrict__ wTg,
        unsigned short* __restrict__ wTd) {
    __shared__ unsigned short lt[64 * 68];
    int z = blockIdx.z;
    int e = blockIdx.y;
    const float* src; unsigned short* dst; int R, C, tr, tc;
    if (z == 0)      { src = w_up;   dst = wTu; R = H_DIM; C = F_DIM; }
    else if (z == 1) { src = w_gate; dst = wTg; R = H_DIM; C = F_DIM; }
    else             { src = w_down; dst = wTd; R = F_DIM; C = H_DIM; }
    if (R == H_DIM) { tc = blockIdx.x & 31; tr = blockIdx.x >> 5; }
    else            { tc = blockIdx.x & 15; tr = blockIdx.x >> 4; }
    const float* s = src + (size_t)e * H_DIM * F_DIM;
    unsigned short* d = dst + (size_t)e * H_DIM * F_DIM;
    int r0 = tr * 64, c0 = tc * 64;
    int tid = threadIdx.x;
    int fc = tid & 15, row = tid >> 4;
#pragma unroll
    for (int i = 0; i < 4; ++i) {
        int r = row + i * 16;
        float4 v = *(const float4*)(s + (size_t)(r0 + r) * C + c0 + fc * 4);
        lt[(fc * 4 + 0) * 68 + r] = f2b(v.x);
        lt[(fc * 4 + 1) * 68 + r] = f2b(v.y);
        lt[(fc * 4 + 2) * 68 + r] = f2b(v.z);
        lt[(fc * 4 + 3) * 68 + r] = f2b(v.w);
    }
    __syncthreads();
    int ch = tid & 7, cc = tid >> 3;
#pragma unroll
    for (int i = 0; i < 2; ++i) {
        int c = cc + i * 32;
        uint2 lo = *(const uint2*)&lt[c * 68 + ch * 8];
        uint2 hi = *(const uint2*)&lt[c * 68 + ch * 8 + 4];
        uint4 o = make_uint4(lo.x, lo.y, hi.x, hi.y);
        *(uint4*)(d + (size_t)(c0 + c) * R + r0 + ch * 8) = o;
    }
}

// =============== up/gate GEMM: 128x128, BK=64, XOR-swizzled LDS (R0 layout), ================
// =============== depth-3 counted-vmcnt pipeline, raw barriers (T3+T4 recipe)  ================
// LDS tile [128 rows][64 k]: pos chunk c (8 elems) of row r holds source chunk c^(r&7);
// staged via linear-LDS gload16 with pre-swizzled global src (rule #21).
#define UPG_STAGE(K0, B) do {                                               \
    _Pragma("unroll")                                                       \
    for (int it_ = 0; it_ < 4; ++it_) {                                     \
        gload16(aB + sOff[it_] + (K0), &la[B][lb_[it_]]);                   \
        gload16(buW + sOff[it_] + (K0), &lbu[B][lb_[it_]]);                 \
        gload16(bgW + sOff[it_] + (K0), &lbg[B][lb_[it_]]);                 \
    }                                                                       \
} while (0)

#define UPG_COMPUTE(B) do {                                                 \
    _Pragma("unroll")                                                       \
    for (int h_ = 0; h_ < 2; ++h_) {                                        \
        bf16x8 af_[4], bu_[4], bg_[4];                                      \
        _Pragma("unroll")                                                   \
        for (int i_ = 0; i_ < 4; ++i_) {                                    \
            int lr = wm * 64 + i_ * 16 + l16;                               \
            af_[i_] = *(const bf16x8*)&la[B][lr * 64 + (((h_ * 4 + quad) ^ (lr & 7)) << 3)]; \
        }                                                                   \
        _Pragma("unroll")                                                   \
        for (int j_ = 0; j_ < 4; ++j_) {                                    \
            int lr = wn * 64 + j_ * 16 + l16;                               \
            int p_ = lr * 64 + (((h_ * 4 + quad) ^ (lr & 7)) << 3);         \
            bu_[j_] = *(const bf16x8*)&lbu[B][p_];                          \
            bg_[j_] = *(const bf16x8*)&lbg[B][p_];                          \
        }                                                                   \
        _Pragma("unroll")                                                   \
        for (int i_ = 0; i_ < 4; ++i_)                                      \
            _Pragma("unroll")                                               \
            for (int j_ = 0; j_ < 4; ++j_) {                                \
                accU[i_][j_] = __builtin_amdgcn_mfma_f32_16x16x32_bf16(af_[i_], bu_[j_], accU[i_][j_], 0, 0, 0); \
                accG[i_][j_] = __builtin_amdgcn_mfma_f32_16x16x32_bf16(af_[i_], bg_[j_], accG[i_][j_], 0, 0, 0); \
            }                                                               \
    }                                                                       \
} while (0)

// wait(tile t ready) -> barrier -> compute -> barrier -> stage(t+3 into same buf)
#define UPG_STEP(T, B) do {                                                 \
    int t_ = (T);                                                           \
    if (t_ <= 13)      asm volatile("s_waitcnt vmcnt(24)" ::: "memory");    \
    else if (t_ == 14) asm volatile("s_waitcnt vmcnt(12)" ::: "memory");    \
    else               asm volatile("s_waitcnt vmcnt(0)"  ::: "memory");    \
    __builtin_amdgcn_s_barrier();                                           \
    __builtin_amdgcn_sched_barrier(0);                                      \
    UPG_COMPUTE(B);                                                         \
    __builtin_amdgcn_sched_barrier(0);                                      \
    __builtin_amdgcn_s_barrier();                                           \
    __builtin_amdgcn_sched_barrier(0);                                      \
    if (t_ + 3 < 16) UPG_STAGE((t_ + 3) * 64, B);                           \
} while (0)

__global__ __launch_bounds__(256, 1) void gemm_upgate_kernel(
        const unsigned short* __restrict__ Xg,
        const unsigned short* __restrict__ wTu,   // [E][F][H] (k-major)
        const unsigned short* __restrict__ wTg,
        unsigned short* __restrict__ inner,       // [TOTROWS][F]
        const int* __restrict__ tileExp, const int* __restrict__ tileM0,
        const int* __restrict__ off, const int* __restrict__ cnt) {
    __shared__ __align__(16) unsigned short la[3][8192];    // 16KB x3
    __shared__ __align__(16) unsigned short lbu[3][8192];
    __shared__ __align__(16) unsigned short lbg[3][8192];   // 144KB total -> 1 block/CU
    int bt = blockIdx.y;
    int e = tileExp[bt];
    if (e < 0) return;
    int m0 = tileM0[bt];
    int r0 = off[e] + m0;
    int valid = cnt[e] - m0;
    int f0 = blockIdx.x * 128;
    const unsigned short* aB  = Xg + (size_t)r0 * H_DIM;
    const unsigned short* buW = wTu + (size_t)e * F_DIM * H_DIM + (size_t)f0 * H_DIM;
    const unsigned short* bgW = wTg + (size_t)e * F_DIM * H_DIM + (size_t)f0 * H_DIM;
    int tid = threadIdx.x;
    int lane = tid & 63, wid = tid >> 6;
    int wm = wid >> 1, wn = wid & 1;
    int l16 = lane & 15, quad = lane >> 4;

    // staging map: chunk = it*256+tid; row = chunk>>3; pre-swizzled source chunk.
    int sOff[4], lb_[4];
#pragma unroll
    for (int it = 0; it < 4; ++it) {
        int chunk = it * 256 + tid;
        int row = chunk >> 3;
        sOff[it] = row * H_DIM + (((chunk & 7) ^ (row & 7)) << 3);
        lb_[it] = it * 2048 + wid * 512;   // ushort idx of wave-uniform LDS base
    }
    f32x4 accU[4][4], accG[4][4];
#pragma unroll
    for (int i = 0; i < 4; ++i)
#pragma unroll
        for (int j = 0; j < 4; ++j) { accU[i][j] = (f32x4)0.f; accG[i][j] = (f32x4)0.f; }

    // prologue: 3 tiles in flight (36 vmem/wave)
    UPG_STAGE(0, 0);
    UPG_STAGE(64, 1);
    UPG_STAGE(128, 2);

    for (int t = 0; t < 15; t += 3) {   // K = 1024 / 64 = 16 tiles
        UPG_STEP(t,     0);
        UPG_STEP(t + 1, 1);
        UPG_STEP(t + 2, 2);
    }
    UPG_STEP(15, 0);

#pragma unroll
    for (int i = 0; i < 4; ++i) {
#pragma unroll
        for (int rr = 0; rr < 4; ++rr) {
            int ml = wm * 64 + i * 16 + quad * 4 + rr;
            if (ml >= valid) continue;
            size_t base = (size_t)(r0 + ml) * F_DIM + f0;
#pragma unroll
            for (int j = 0; j < 4; ++j) {
                float u = accU[i][j][rr];
                float g = accG[i][j][rr];
                float v = u * __builtin_amdgcn_rcpf(1.f + __expf(-u)) * g;   // silu(up)*gate
                inner[base + wn * 64 + j * 16 + l16] = f2b(v);
            }
        }
    }
}

// =============== down GEMM: 128x128, BK=64, XOR-swizzled, depth-2 counted vmcnt ==============
#define DWN_STAGE(K0, B) do {                                               \
    _Pragma("unroll")                                                       \
    for (int it_ = 0; it_ < 4; ++it_) {                                     \
        gload16(aB + sOff[it_] + (K0), &la[B][lb_[it_]]);                   \
        gload16(bp + sOff[it_] + (K0), &lb[B][lb_[it_]]);                   \
    }                                                                       \
} while (0)

#define DWN_COMPUTE(B) do {                                                 \
    _Pragma("unroll")                                                       \
    for (int h_ = 0; h_ < 2; ++h_) {                                        \
        bf16x8 af_[4], bw_[4];                                              \
        _Pragma("unroll")                                                   \
        for (int i_ = 0; i_ < 4; ++i_) {                                    \
            int lr = wm * 64 + i_ * 16 + l16;                               \
            af_[i_] = *(const bf16x8*)&la[B][lr * 64 + (((h_ * 4 + quad) ^ (lr & 7)) << 3)]; \
        }                                                                   \
        _Pragma("unroll")                                                   \
        for (int j_ = 0; j_ < 4; ++j_) {                                    \
            int lr = wn * 64 + j_ * 16 + l16;                               \
            bw_[j_] = *(const bf16x8*)&lb[B][lr * 64 + (((h_ * 4 + quad) ^ (lr & 7)) << 3)]; \
        }                                                                   \
        _Pragma("unroll")                                                   \
        for (int i_ = 0; i_ < 4; ++i_)                                      \
            _Pragma("unroll")                                               \
            for (int j_ = 0; j_ < 4; ++j_)                                  \
                acc[i_][j_] = __builtin_amdgcn_mfma_f32_16x16x32_bf16(af_[i_], bw_[j_], acc[i_][j_], 0, 0, 0); \
    }                                                                       \
} while (0)

#define DWN_STEP(T, B) do {                                                 \
    int t_ = (T);                                                           \
    if (t_ != 31) asm volatile("s_waitcnt vmcnt(8)" ::: "memory");          \
    else          asm volatile("s_waitcnt vmcnt(0)" ::: "memory");          \
    __builtin_amdgcn_s_barrier();                                           \
    __builtin_amdgcn_sched_barrier(0);                                      \
    DWN_COMPUTE(B);                                                         \
    __builtin_amdgcn_sched_barrier(0);                                      \
    __builtin_amdgcn_s_barrier();                                           \
    __builtin_amdgcn_sched_barrier(0);                                      \
    if (t_ + 2 < 32) DWN_STAGE((t_ + 2) * 64, B);                           \
} while (0)

__global__ __launch_bounds__(256, 2) void gemm_down_kernel(
        const unsigned short* __restrict__ inner,  // [TOTROWS][F]
        const unsigned short* __restrict__ wTd,    // [E][H][F] (k-major)
        float* __restrict__ part,                  // [TOTROWS][H]
        const int* __restrict__ tileExp, const int* __restrict__ tileM0,
        const int* __restrict__ off, const int* __restrict__ cnt,
        const float* __restrict__ rowWgt) {
    __shared__ __align__(16) unsigned short la[2][8192];   // 16KB x2
    __shared__ __align__(16) unsigned short lb[2][8192];   // 64KB -> 2 blocks/CU
    int bt = blockIdx.y;
    int e = tileExp[bt];
    if (e < 0) return;
    int m0 = tileM0[bt];
    int r0 = off[e] + m0;
    int valid = cnt[e] - m0;
    int h0 = blockIdx.x * 128;
    const unsigned short* aB = inner + (size_t)r0 * F_DIM;
    const unsigned short* bp = wTd + (size_t)e * H_DIM * F_DIM + (size_t)h0 * F_DIM;
    int tid = threadIdx.x;
    int lane = tid & 63, wid = tid >> 6;
    int wm = wid >> 1, wn = wid & 1;
    int l16 = lane & 15, quad = lane >> 4;

    int sOff[4], lb_[4];
#pragma unroll
    for (int it = 0; it < 4; ++it) {
        int chunk = it * 256 + tid;
        int row = chunk >> 3;
        sOff[it] = row * F_DIM + (((chunk & 7) ^ (row & 7)) << 3);
        lb_[it] = it * 2048 + wid * 512;
    }
    f32x4 acc[4][4];
#pragma unroll
    for (int i = 0; i < 4; ++i)
#pragma unroll
        for (int j = 0; j < 4; ++j) acc[i][j] = (f32x4)0.f;

    // prologue: 2 tiles in flight (16 vmem/wave)
    DWN_STAGE(0, 0);
    DWN_STAGE(64, 1);

    for (int t = 0; t < 32; t += 2) {   // K = 2048 / 64 = 32 tiles
        DWN_STEP(t,     0);
        DWN_STEP(t + 1, 1);
    }

#pragma unroll
    for (int i = 0; i < 4; ++i) {
#pragma unroll
        for (int rr = 0; rr < 4; ++rr) {
            int ml = wm * 64 + i * 16 + quad * 4 + rr;
            if (ml >= valid) continue;
            int gr = r0 + ml;
            float w = rowWgt[gr];
            float* orow = part + (size_t)gr * H_DIM + h0;
#pragma unroll
            for (int j = 0; j < 4; ++j)
                orow[wn * 64 + j * 16 + l16] = w * acc[i][j][rr];
        }
    }
}

// ---------------- combine: out[t] = part[r1] + part[r2] ----------------
__global__ __launch_bounds__(256) void combine_kernel(const float* __restrict__ part,
                                                      const int* __restrict__ tokRow,
                                                      float* __restrict__ out) {
    int t = blockIdx.x;
    int r1 = tokRow[t * 2 + 0], r2 = tokRow[t * 2 + 1];
    int i = threadIdx.x;
    float4 a = ((const float4*)(part + (size_t)r1 * H_DIM))[i];
    float4 b = ((const float4*)(part + (size_t)r2 * H_DIM))[i];
    float4 o;
    o.x = a.x + b.x; o.y = a.y + b.y; o.z = a.z + b.z; o.w = a.w + b.w;
    ((float4*)(out + (size_t)t * H_DIM))[i] = o;
}

extern "C" void kernel_launch(void* const* d_in, const int* in_sizes, int n_in,
                              void* d_out, int out_size, void* d_ws, size_t ws_size,
                              hipStream_t stream) {
    const float* x      = (const float*)d_in[0];
    const float* gw     = (const float*)d_in[1];
    const float* w_up   = (const float*)d_in[2];
    const float* w_gate = (const float*)d_in[3];
    const float* w_down = (const float*)d_in[4];
    float* out = (float*)d_out;

    char* ws = (char*)d_ws;
    size_t o = 0;
    unsigned short* wTu = (unsigned short*)(ws + o); o += (size_t)NEXP * F_DIM * H_DIM * 2;
    unsigned short* wTg = (unsigned short*)(ws + o); o += (size_t)NEXP * F_DIM * H_DIM * 2;
    unsigned short* wTd = (unsigned short*)(ws + o); o += (size_t)NEXP * H_DIM * F_DIM * 2;
    unsigned short* Xg  = (unsigned short*)(ws + o); o += (size_t)TOTROWS * H_DIM * 2;
    unsigned short* inner = (unsigned short*)(ws + o); o += (size_t)TOTROWS * F_DIM * 2;
    o += 1024 * 1024;  // pad: tail-row overreads past inner stay in ws
    float* rowWgt = (float*)(ws + o); o += TOTROWS * 4;
    int*   tokRow = (int*)(ws + o);   o += T_TOK * 2 * 4;
    int*   sel    = (int*)(ws + o);   o += T_TOK * 2 * 4;
    float* selw   = (float*)(ws + o); o += T_TOK * 2 * 4;
    int*   cnt    = (int*)(ws + o);   o += 8 * 4;
    int*   fill   = (int*)(ws + o);   o += 8 * 4;
    int*   off_   = (int*)(ws + o);   o += 8 * 4;
    int*   tileExp = (int*)(ws + o);  o += MAXTILES * 4;
    int*   tileM0  = (int*)(ws + o);  o += MAXTILES * 4;
    // part[TOTROWS][H] fp32 aliases wTu+wTg (dead after gemm_upgate; stream-serial)
    float* part = (float*)wTu;

    router_kernel<<<T_TOK / 4, 256, 0, stream>>>(x, gw, sel, selw);
    scan_kernel<<<1, 256, 0, stream>>>(sel, cnt, off_, fill, tileExp, tileM0);
    scatgath_kernel<<<T_TOK, 256, 0, stream>>>(sel, selw, off_, fill, rowWgt, tokRow, x, Xg);
    transpose_cvt_kernel<<<dim3(512, NEXP, 3), 256, 0, stream>>>(w_up, w_gate, w_down, wTu, wTg, wTd);
    gemm_upgate_kernel<<<dim3(F_DIM / 128, 72), 256, 0, stream>>>(Xg, wTu, wTg, inner, tileExp, tileM0, off_, cnt);
    gemm_down_kernel<<<dim3(H_DIM / 128, 72), 256, 0, stream>>>(inner, wTd, part, tileExp, tileM0, off_, cnt, rowWgt);
    combine_kernel<<<T_TOK, 256, 0, stream>>>(part, tokRow, out);
}

// Round 3
// 532.545 us; speedup vs baseline: 1.2040x; 1.0793x over previous
//
#include <hip/hip_runtime.h>
#include <hip/hip_bf16.h>

typedef __bf16 bf16x8 __attribute__((ext_vector_type(8)));
typedef float f32x4 __attribute__((ext_vector_type(4)));

#define T_TOK 4096
#define H_DIM 1024
#define F_DIM 2048
#define NEXP 8
#define TOTROWS 8192   // T_TOK * TOP_K, always exact (top-2 distinct experts)
#define MAXTILES 80    // 128-row tiles (down)
#define UPT 40         // 256-row tiles (upgate): worst case 32+7 = 39

__device__ inline unsigned short f2b(float f) {
    unsigned int u = __float_as_uint(f);
    unsigned int r = (u + 0x7fffu + ((u >> 16) & 1u)) >> 16;
    return (unsigned short)r;
}

// async global->LDS, 16B per lane. LDS dst = wave-uniform base + lane*16.
__device__ inline void gload16(const void* g, void* l) {
    __builtin_amdgcn_global_load_lds(
        (const __attribute__((address_space(1))) unsigned int*)g,
        (__attribute__((address_space(3))) unsigned int*)l,
        16, 0, 0);
}

// ---------------- router: logits -> softmax -> top2 -> renorm (4 tokens/block, no atomics) ----
__global__ __launch_bounds__(256) void router_kernel(const float* __restrict__ x,
                                                     const float* __restrict__ gw,
                                                     int* __restrict__ sel, float* __restrict__ selw) {
    int t = blockIdx.x * 4 + (threadIdx.x >> 6);
    int lane = threadIdx.x & 63;
    float acc[8] = {0.f,0.f,0.f,0.f,0.f,0.f,0.f,0.f};
    const float* xr = x + (size_t)t * H_DIM;
    for (int h = lane; h < H_DIM; h += 64) {
        float xv = xr[h];
        const float4* g = (const float4*)(gw + h * 8);
        float4 g0 = g[0], g1 = g[1];
        acc[0] += xv * g0.x; acc[1] += xv * g0.y; acc[2] += xv * g0.z; acc[3] += xv * g0.w;
        acc[4] += xv * g1.x; acc[5] += xv * g1.y; acc[6] += xv * g1.z; acc[7] += xv * g1.w;
    }
#pragma unroll
    for (int off = 32; off >= 1; off >>= 1)
#pragma unroll
        for (int e = 0; e < 8; ++e)
            acc[e] += __shfl_down(acc[e], off);
    if (lane == 0) {
        float mx = acc[0];
#pragma unroll
        for (int e = 1; e < 8; ++e) mx = fmaxf(mx, acc[e]);
        float p[8]; float s = 0.f;
#pragma unroll
        for (int e = 0; e < 8; ++e) { p[e] = expf(acc[e] - mx); s += p[e]; }
        float inv_s = 1.f / s;
#pragma unroll
        for (int e = 0; e < 8; ++e) p[e] *= inv_s;
        int e1 = 0; float p1 = p[0];
#pragma unroll
        for (int e = 1; e < 8; ++e) if (p[e] > p1) { p1 = p[e]; e1 = e; }
        int e2 = -1; float p2 = -1.f;
#pragma unroll
        for (int e = 0; e < 8; ++e) { if (e == e1) continue; if (p[e] > p2) { p2 = p[e]; e2 = e; } }
        float inv = 1.f / (p1 + p2);
        sel[t * 2 + 0] = e1; sel[t * 2 + 1] = e2;
        selw[t * 2 + 0] = p1 * inv; selw[t * 2 + 1] = p2 * inv;
    }
}

// ---------------- scan: histogram sel -> cnt/off/fill + BOTH tile tables (1 block) ----------
__global__ __launch_bounds__(256) void scan_kernel(const int* __restrict__ sel,
                                                   int* __restrict__ cnt, int* __restrict__ off,
                                                   int* __restrict__ fill,
                                                   int* __restrict__ tileExp, int* __restrict__ tileM0,
                                                   int* __restrict__ tileExpU, int* __restrict__ tileM0U) {
    __shared__ int h[NEXP];
    int tid = threadIdx.x;
    if (tid < NEXP) h[tid] = 0;
    __syncthreads();
    for (int i = tid; i < TOTROWS; i += 256) atomicAdd(&h[sel[i]], 1);
    __syncthreads();
    if (tid == 0) {
        int o = 0;
        for (int e = 0; e < NEXP; ++e) { cnt[e] = h[e]; off[e] = o; o += h[e]; fill[e] = 0; }
        int nt = 0;
        for (int e = 0; e < NEXP; ++e)
            for (int m0 = 0; m0 < h[e]; m0 += 128) { tileExp[nt] = e; tileM0[nt] = m0; nt++; }
        for (int i = nt; i < MAXTILES; ++i) { tileExp[i] = -1; tileM0[i] = 0; }
        int nu = 0;
        for (int e = 0; e < NEXP; ++e)
            for (int m0 = 0; m0 < h[e]; m0 += 256) { tileExpU[nu] = e; tileM0U[nu] = m0; nu++; }
        for (int i = nu; i < UPT; ++i) { tileExpU[i] = -1; tileM0U[i] = 0; }
    }
}

// ---------------- fused scatter+gather: slots + copy x row (bf16) to both expert rows --------
__global__ __launch_bounds__(256) void scatgath_kernel(const int* __restrict__ sel,
                                                       const float* __restrict__ selw,
                                                       const int* __restrict__ off,
                                                       int* __restrict__ fill,
                                                       float* __restrict__ rowWgt,
                                                       int* __restrict__ tokRow,
                                                       const float* __restrict__ x,
                                                       unsigned short* __restrict__ Xg) {
    __shared__ int rs[2];
    int t = blockIdx.x;
    int tid = threadIdx.x;
    if (tid == 0) {
#pragma unroll
        for (int k = 0; k < 2; ++k) {
            int e = sel[t * 2 + k];
            int slot = atomicAdd(&fill[e], 1);
            int r = off[e] + slot;
            rowWgt[r] = selw[t * 2 + k];
            tokRow[t * 2 + k] = r;
            rs[k] = r;
        }
    }
    __syncthreads();
    int r1 = rs[0], r2 = rs[1];
    float4 v = ((const float4*)(x + (size_t)t * H_DIM))[tid];
    ushort4 o;
    o.x = f2b(v.x); o.y = f2b(v.y); o.z = f2b(v.z); o.w = f2b(v.w);
    ((ushort4*)(Xg + (size_t)r1 * H_DIM))[tid] = o;
    ((ushort4*)(Xg + (size_t)r2 * H_DIM))[tid] = o;
}

// ---------------- fused transpose+cvt for all 3 weight tensors ----------------
__global__ __launch_bounds__(256) void transpose_cvt_kernel(
        const float* __restrict__ w_up, const float* __restrict__ w_gate,
        const float* __restrict__ w_down,
        unsigned short* __restrict__ wTu, unsigned short* __restrict__ wTg,
        unsigned short* __restrict__ wTd) {
    __shared__ unsigned short lt[64 * 68];
    int z = blockIdx.z;
    int e = blockIdx.y;
    const float* src; unsigned short* dst; int R, C, tr, tc;
    if (z == 0)      { src = w_up;   dst = wTu; R = H_DIM; C = F_DIM; }
    else if (z == 1) { src = w_gate; dst = wTg; R = H_DIM; C = F_DIM; }
    else             { src = w_down; dst = wTd; R = F_DIM; C = H_DIM; }
    if (R == H_DIM) { tc = blockIdx.x & 31; tr = blockIdx.x >> 5; }
    else            { tc = blockIdx.x & 15; tr = blockIdx.x >> 4; }
    const float* s = src + (size_t)e * H_DIM * F_DIM;
    unsigned short* d = dst + (size_t)e * H_DIM * F_DIM;
    int r0 = tr * 64, c0 = tc * 64;
    int tid = threadIdx.x;
    int fc = tid & 15, row = tid >> 4;
#pragma unroll
    for (int i = 0; i < 4; ++i) {
        int r = row + i * 16;
        float4 v = *(const float4*)(s + (size_t)(r0 + r) * C + c0 + fc * 4);
        lt[(fc * 4 + 0) * 68 + r] = f2b(v.x);
        lt[(fc * 4 + 1) * 68 + r] = f2b(v.y);
        lt[(fc * 4 + 2) * 68 + r] = f2b(v.z);
        lt[(fc * 4 + 3) * 68 + r] = f2b(v.w);
    }
    __syncthreads();
    int ch = tid & 7, cc = tid >> 3;
#pragma unroll
    for (int i = 0; i < 2; ++i) {
        int c = cc + i * 32;
        uint2 lo = *(const uint2*)&lt[c * 68 + ch * 8];
        uint2 hi = *(const uint2*)&lt[c * 68 + ch * 8 + 4];
        uint4 o = make_uint4(lo.x, lo.y, hi.x, hi.y);
        *(uint4*)(d + (size_t)(c0 + c) * R + r0 + ch * 8) = o;
    }
}

// =============== up/gate GEMM: 256x128, BK=64, 512 thr / 8 waves (4M x 2N), =================
// =============== dbuf + depth-2 counted vmcnt(8), raw barriers, XOR-swizzled LDS ============
#define UPG_STAGE(K0, B) do {                                                \
    _Pragma("unroll")                                                        \
    for (int it_ = 0; it_ < 4; ++it_)                                        \
        gload16(aB + sOffA[it_] + (K0), &la[B][lbA[it_]]);                   \
    _Pragma("unroll")                                                        \
    for (int it_ = 0; it_ < 2; ++it_) {                                      \
        gload16(buW + sOffB[it_] + (K0), &lbu[B][lbB[it_]]);                 \
        gload16(bgW + sOffB[it_] + (K0), &lbg[B][lbB[it_]]);                 \
    }                                                                        \
} while (0)

#define UPG_COMPUTE(B) do {                                                  \
    _Pragma("unroll")                                                        \
    for (int h_ = 0; h_ < 2; ++h_) {                                         \
        bf16x8 af_[4], bu_[4], bg_[4];                                       \
        _Pragma("unroll")                                                    \
        for (int i_ = 0; i_ < 4; ++i_) {                                     \
            int lr = wm * 64 + i_ * 16 + l16;                                \
            af_[i_] = *(const bf16x8*)&la[B][lr * 64 + (((h_ * 4 + quad) ^ (lr & 7)) << 3)]; \
        }                                                                    \
        _Pragma("unroll")                                                    \
        for (int j_ = 0; j_ < 4; ++j_) {                                     \
            int lr = wn * 64 + j_ * 16 + l16;                                \
            int p_ = lr * 64 + (((h_ * 4 + quad) ^ (lr & 7)) << 3);          \
            bu_[j_] = *(const bf16x8*)&lbu[B][p_];                           \
            bg_[j_] = *(const bf16x8*)&lbg[B][p_];                           \
        }                                                                    \
        _Pragma("unroll")                                                    \
        for (int i_ = 0; i_ < 4; ++i_)                                       \
            _Pragma("unroll")                                                \
            for (int j_ = 0; j_ < 4; ++j_) {                                 \
                accU[i_][j_] = __builtin_amdgcn_mfma_f32_16x16x32_bf16(af_[i_], bu_[j_], accU[i_][j_], 0, 0, 0); \
                accG[i_][j_] = __builtin_amdgcn_mfma_f32_16x16x32_bf16(af_[i_], bg_[j_], accG[i_][j_], 0, 0, 0); \
            }                                                                \
    }                                                                        \
} while (0)

__global__ __launch_bounds__(512, 2) void gemm_upgate_kernel(
        const unsigned short* __restrict__ Xg,
        const unsigned short* __restrict__ wTu,   // [E][F][H] (k-major)
        const unsigned short* __restrict__ wTg,
        unsigned short* __restrict__ inner,       // [TOTROWS][F]
        const int* __restrict__ tileExpU, const int* __restrict__ tileM0U,
        const int* __restrict__ off, const int* __restrict__ cnt) {
    __shared__ __align__(16) unsigned short la[2][16384];   // 32KB x2 (256x64)
    __shared__ __align__(16) unsigned short lbu[2][8192];   // 16KB x2 (128x64)
    __shared__ __align__(16) unsigned short lbg[2][8192];   // total 128KB -> 1 block/CU, 2 w/SIMD
    int bt = blockIdx.y;
    int e = tileExpU[bt];
    if (e < 0) return;
    int m0 = tileM0U[bt];
    int r0 = off[e] + m0;
    int valid = cnt[e] - m0;
    int f0 = blockIdx.x * 128;
    const unsigned short* aB  = Xg + (size_t)r0 * H_DIM;
    const unsigned short* buW = wTu + (size_t)e * F_DIM * H_DIM + (size_t)f0 * H_DIM;
    const unsigned short* bgW = wTg + (size_t)e * F_DIM * H_DIM + (size_t)f0 * H_DIM;
    int tid = threadIdx.x;
    int lane = tid & 63, wid = tid >> 6;   // 8 waves
    int wm = wid >> 1, wn = wid & 1;       // 4M x 2N -> 64x64 per wave
    int l16 = lane & 15, quad = lane >> 4;

    // staging maps (pre-swizzled global src, linear LDS dst; rule #21)
    int sOffA[4], lbA[4], sOffB[2], lbB[2];
#pragma unroll
    for (int it = 0; it < 4; ++it) {             // A: 256 rows x 64 k = 2048 chunks
        int chunk = it * 512 + tid;
        int row = chunk >> 3;
        sOffA[it] = row * H_DIM + (((chunk & 7) ^ (row & 7)) << 3);
        lbA[it] = it * 4096 + wid * 512;         // ushort idx, wave-uniform
    }
#pragma unroll
    for (int it = 0; it < 2; ++it) {             // B: 128 rows x 64 k = 1024 chunks
        int chunk = it * 512 + tid;
        int row = chunk >> 3;
        sOffB[it] = row * H_DIM + (((chunk & 7) ^ (row & 7)) << 3);
        lbB[it] = it * 4096 + wid * 512;
    }
    f32x4 accU[4][4], accG[4][4];
#pragma unroll
    for (int i = 0; i < 4; ++i)
#pragma unroll
        for (int j = 0; j < 4; ++j) { accU[i][j] = (f32x4)0.f; accG[i][j] = (f32x4)0.f; }

    // prologue: 2 K-tiles in flight (16 loads/wave)
    UPG_STAGE(0, 0);
    UPG_STAGE(64, 1);

    // steady state: wait(own oldest 8 = tile t landed), barrier, compute, barrier,
    // then restage freed buffer with tile t+2. vmcnt never 0 until drain.
    for (int t = 0; t < 14; ++t) {
        asm volatile("s_waitcnt vmcnt(8)" ::: "memory");
        __builtin_amdgcn_s_barrier();
        __builtin_amdgcn_sched_barrier(0);
        __builtin_amdgcn_s_setprio(1);
        UPG_COMPUTE(t & 1);
        __builtin_amdgcn_s_setprio(0);
        __builtin_amdgcn_sched_barrier(0);
        __builtin_amdgcn_s_barrier();
        __builtin_amdgcn_sched_barrier(0);
        UPG_STAGE((t + 2) * 64, t & 1);
    }
    asm volatile("s_waitcnt vmcnt(8)" ::: "memory");   // tile 14 landed
    __builtin_amdgcn_s_barrier();
    __builtin_amdgcn_sched_barrier(0);
    UPG_COMPUTE(0);
    __builtin_amdgcn_s_barrier();
    asm volatile("s_waitcnt vmcnt(0)" ::: "memory");   // tile 15 landed
    __builtin_amdgcn_s_barrier();
    __builtin_amdgcn_sched_barrier(0);
    UPG_COMPUTE(1);

#pragma unroll
    for (int i = 0; i < 4; ++i) {
#pragma unroll
        for (int rr = 0; rr < 4; ++rr) {
            int ml = wm * 64 + i * 16 + quad * 4 + rr;
            if (ml >= valid) continue;
            size_t base = (size_t)(r0 + ml) * F_DIM + f0;
#pragma unroll
            for (int j = 0; j < 4; ++j) {
                float u = accU[i][j][rr];
                float g = accG[i][j][rr];
                float v = u * __builtin_amdgcn_rcpf(1.f + __expf(-u)) * g;   // silu(up)*gate
                inner[base + wn * 64 + j * 16 + l16] = f2b(v);
            }
        }
    }
}

// =============== down GEMM: 128x128, BK=64, 512 thr / 8 waves (2M x 4N), 2 blocks/CU ========
#define DWN_STAGE(K0, B) do {                                                \
    _Pragma("unroll")                                                        \
    for (int it_ = 0; it_ < 2; ++it_) {                                      \
        gload16(aB + sOff[it_] + (K0), &la[B][lb_[it_]]);                    \
        gload16(bp + sOff[it_] + (K0), &lb[B][lb_[it_]]);                    \
    }                                                                        \
} while (0)

#define DWN_COMPUTE(B) do {                                                  \
    _Pragma("unroll")                                                        \
    for (int h_ = 0; h_ < 2; ++h_) {                                         \
        bf16x8 af_[4], bw_[2];                                               \
        _Pragma("unroll")                                                    \
        for (int i_ = 0; i_ < 4; ++i_) {                                     \
            int lr = wm * 64 + i_ * 16 + l16;                                \
            af_[i_] = *(const bf16x8*)&la[B][lr * 64 + (((h_ * 4 + quad) ^ (lr & 7)) << 3)]; \
        }                                                                    \
        _Pragma("unroll")                                                    \
        for (int j_ = 0; j_ < 2; ++j_) {                                     \
            int lr = wn * 32 + j_ * 16 + l16;                                \
            bw_[j_] = *(const bf16x8*)&lb[B][lr * 64 + (((h_ * 4 + quad) ^ (lr & 7)) << 3)]; \
        }                                                                    \
        _Pragma("unroll")                                                    \
        for (int i_ = 0; i_ < 4; ++i_)                                       \
            _Pragma("unroll")                                                \
            for (int j_ = 0; j_ < 2; ++j_)                                   \
                acc[i_][j_] = __builtin_amdgcn_mfma_f32_16x16x32_bf16(af_[i_], bw_[j_], acc[i_][j_], 0, 0, 0); \
    }                                                                        \
} while (0)

__global__ __launch_bounds__(512, 4) void gemm_down_kernel(
        const unsigned short* __restrict__ inner,  // [TOTROWS][F]
        const unsigned short* __restrict__ wTd,    // [E][H][F] (k-major)
        float* __restrict__ part,                  // [TOTROWS][H]
        const int* __restrict__ tileExp, const int* __restrict__ tileM0,
        const int* __restrict__ off, const int* __restrict__ cnt,
        const float* __restrict__ rowWgt) {
    __shared__ __align__(16) unsigned short la[2][8192];   // 16KB x2 (128x64)
    __shared__ __align__(16) unsigned short lb[2][8192];   // 64KB total -> 2 blocks/CU
    int bt = blockIdx.y;
    int e = tileExp[bt];
    if (e < 0) return;
    int m0 = tileM0[bt];
    int r0 = off[e] + m0;
    int valid = cnt[e] - m0;
    int h0 = blockIdx.x * 128;
    const unsigned short* aB = inner + (size_t)r0 * F_DIM;
    const unsigned short* bp = wTd + (size_t)e * H_DIM * F_DIM + (size_t)h0 * F_DIM;
    int tid = threadIdx.x;
    int lane = tid & 63, wid = tid >> 6;   // 8 waves
    int wm = wid >> 2, wn = wid & 3;       // 2M x 4N -> 64x32 per wave
    int l16 = lane & 15, quad = lane >> 4;

    int sOff[2], lb_[2];
#pragma unroll
    for (int it = 0; it < 2; ++it) {       // 128 rows x 64 k = 1024 chunks
        int chunk = it * 512 + tid;
        int row = chunk >> 3;
        sOff[it] = row * F_DIM + (((chunk & 7) ^ (row & 7)) << 3);
        lb_[it] = it * 4096 + wid * 512;
    }
    f32x4 acc[4][2];
#pragma unroll
    for (int i = 0; i < 4; ++i)
#pragma unroll
        for (int j = 0; j < 2; ++j) acc[i][j] = (f32x4)0.f;

    DWN_STAGE(0, 0);
    DWN_STAGE(64, 1);

    for (int t = 0; t < 30; ++t) {         // K = 2048 / 64 = 32 tiles
        asm volatile("s_waitcnt vmcnt(4)" ::: "memory");
        __builtin_amdgcn_s_barrier();
        __builtin_amdgcn_sched_barrier(0);
        __builtin_amdgcn_s_setprio(1);
        DWN_COMPUTE(t & 1);
        __builtin_amdgcn_s_setprio(0);
        __builtin_amdgcn_sched_barrier(0);
        __builtin_amdgcn_s_barrier();
        __builtin_amdgcn_sched_barrier(0);
        DWN_STAGE((t + 2) * 64, t & 1);
    }
    asm volatile("s_waitcnt vmcnt(4)" ::: "memory");   // tile 30 landed
    __builtin_amdgcn_s_barrier();
    __builtin_amdgcn_sched_barrier(0);
    DWN_COMPUTE(0);
    __builtin_amdgcn_s_barrier();
    asm volatile("s_waitcnt vmcnt(0)" ::: "memory");   // tile 31 landed
    __builtin_amdgcn_s_barrier();
    __builtin_amdgcn_sched_barrier(0);
    DWN_COMPUTE(1);

#pragma unroll
    for (int i = 0; i < 4; ++i) {
#pragma unroll
        for (int rr = 0; rr < 4; ++rr) {
            int ml = wm * 64 + i * 16 + quad * 4 + rr;
            if (ml >= valid) continue;
            int gr = r0 + ml;
            float w = rowWgt[gr];
            float* orow = part + (size_t)gr * H_DIM + h0;
#pragma unroll
            for (int j = 0; j < 2; ++j)
                orow[wn * 32 + j * 16 + l16] = w * acc[i][j][rr];
        }
    }
}

// ---------------- combine: out[t] = part[r1] + part[r2] ----------------
__global__ __launch_bounds__(256) void combine_kernel(const float* __restrict__ part,
                                                      const int* __restrict__ tokRow,
                                                      float* __restrict__ out) {
    int t = blockIdx.x;
    int r1 = tokRow[t * 2 + 0], r2 = tokRow[t * 2 + 1];
    int i = threadIdx.x;
    float4 a = ((const float4*)(part + (size_t)r1 * H_DIM))[i];
    float4 b = ((const float4*)(part + (size_t)r2 * H_DIM))[i];
    float4 o;
    o.x = a.x + b.x; o.y = a.y + b.y; o.z = a.z + b.z; o.w = a.w + b.w;
    ((float4*)(out + (size_t)t * H_DIM))[i] = o;
}

extern "C" void kernel_launch(void* const* d_in, const int* in_sizes, int n_in,
                              void* d_out, int out_size, void* d_ws, size_t ws_size,
                              hipStream_t stream) {
    const float* x      = (const float*)d_in[0];
    const float* gw     = (const float*)d_in[1];
    const float* w_up   = (const float*)d_in[2];
    const float* w_gate = (const float*)d_in[3];
    const float* w_down = (const float*)d_in[4];
    float* out = (float*)d_out;

    char* ws = (char*)d_ws;
    size_t o = 0;
    unsigned short* wTu = (unsigned short*)(ws + o); o += (size_t)NEXP * F_DIM * H_DIM * 2;
    unsigned short* wTg = (unsigned short*)(ws + o); o += (size_t)NEXP * F_DIM * H_DIM * 2;
    unsigned short* wTd = (unsigned short*)(ws + o); o += (size_t)NEXP * H_DIM * F_DIM * 2;
    unsigned short* Xg  = (unsigned short*)(ws + o); o += (size_t)TOTROWS * H_DIM * 2;
    unsigned short* inner = (unsigned short*)(ws + o); o += (size_t)TOTROWS * F_DIM * 2;
    o += 2 * 1024 * 1024;  // pad: 255-row tail overreads (up to ~1.04MB) stay in ws
    float* rowWgt = (float*)(ws + o); o += TOTROWS * 4;
    int*   tokRow = (int*)(ws + o);   o += T_TOK * 2 * 4;
    int*   sel    = (int*)(ws + o);   o += T_TOK * 2 * 4;
    float* selw   = (float*)(ws + o); o += T_TOK * 2 * 4;
    int*   cnt    = (int*)(ws + o);   o += 8 * 4;
    int*   fill   = (int*)(ws + o);   o += 8 * 4;
    int*   off_   = (int*)(ws + o);   o += 8 * 4;
    int*   tileExp = (int*)(ws + o);  o += MAXTILES * 4;
    int*   tileM0  = (int*)(ws + o);  o += MAXTILES * 4;
    int*   tileExpU = (int*)(ws + o); o += UPT * 4;
    int*   tileM0U  = (int*)(ws + o); o += UPT * 4;
    // part[TOTROWS][H] fp32 aliases wTu+wTg (dead after gemm_upgate; stream-serial)
    float* part = (float*)wTu;

    router_kernel<<<T_TOK / 4, 256, 0, stream>>>(x, gw, sel, selw);
    scan_kernel<<<1, 256, 0, stream>>>(sel, cnt, off_, fill, tileExp, tileM0, tileExpU, tileM0U);
    scatgath_kernel<<<T_TOK, 256, 0, stream>>>(sel, selw, off_, fill, rowWgt, tokRow, x, Xg);
    transpose_cvt_kernel<<<dim3(512, NEXP, 3), 256, 0, stream>>>(w_up, w_gate, w_down, wTu, wTg, wTd);
    gemm_upgate_kernel<<<dim3(F_DIM / 128, UPT), 512, 0, stream>>>(Xg, wTu, wTg, inner, tileExpU, tileM0U, off_, cnt);
    gemm_down_kernel<<<dim3(H_DIM / 128, 72), 512, 0, stream>>>(inner, wTd, part, tileExp, tileM0, off_, cnt, rowWgt);
    combine_kernel<<<T_TOK, 256, 0, stream>>>(part, tokRow, out);
}

// Round 4
// 515.765 us; speedup vs baseline: 1.2431x; 1.0325x over previous
//
#include <hip/hip_runtime.h>
#include <hip/hip_bf16.h>

typedef __bf16 bf16x8 __attribute__((ext_vector_type(8)));
typedef float f32x4 __attribute__((ext_vector_type(4)));

#define T_TOK 4096
#define H_DIM 1024
#define F_DIM 2048
#define NEXP 8
#define TOTROWS 8192   // T_TOK * TOP_K, always exact (top-2 distinct experts)
#define MAXTILES 80    // 128-row tiles (down)
#define UPT 40         // 256-row tiles (upgate): worst case 32+7 = 39

__device__ inline unsigned short f2b(float f) {
    unsigned int u = __float_as_uint(f);
    unsigned int r = (u + 0x7fffu + ((u >> 16) & 1u)) >> 16;
    return (unsigned short)r;
}

// async global->LDS, 16B per lane. LDS dst = wave-uniform base + lane*16.
__device__ inline void gload16(const void* g, void* l) {
    __builtin_amdgcn_global_load_lds(
        (const __attribute__((address_space(1))) unsigned int*)g,
        (__attribute__((address_space(3))) unsigned int*)l,
        16, 0, 0);
}

// BK=32 super-row swizzle: two 64B rows share one 128B line. 16B slot p:
//   sr=p>>3, s=p&7, qq=s^(sr&7), r=2*sr+(qq>>2), q=qq&3  -> src elem r*LD+q*8.
// Fragment read (row lr, k-chunk quad): ushort idx =
//   (lr>>1)*64 + (((quad | ((lr&1)<<2)) ^ ((lr>>1)&7)) << 3).
// 16-lane fragment groups hit each 16B bank-group exactly 2x -> 2-way = free.
__device__ inline int swz_src(int p, int LD) {
    int sr = p >> 3, s = p & 7;
    int qq = s ^ (sr & 7);
    int r = 2 * sr + (qq >> 2);
    int q = qq & 3;
    return r * LD + q * 8;
}
__device__ inline int swz_frag(int lr, int quad) {
    return (lr >> 1) * 64 + (((quad | ((lr & 1) << 2)) ^ ((lr >> 1) & 7)) << 3);
}

// ---------------- router: logits -> softmax -> top2 -> renorm (4 tokens/block, no atomics) ----
__global__ __launch_bounds__(256) void router_kernel(const float* __restrict__ x,
                                                     const float* __restrict__ gw,
                                                     int* __restrict__ sel, float* __restrict__ selw) {
    int t = blockIdx.x * 4 + (threadIdx.x >> 6);
    int lane = threadIdx.x & 63;
    float acc[8] = {0.f,0.f,0.f,0.f,0.f,0.f,0.f,0.f};
    const float* xr = x + (size_t)t * H_DIM;
    for (int h = lane; h < H_DIM; h += 64) {
        float xv = xr[h];
        const float4* g = (const float4*)(gw + h * 8);
        float4 g0 = g[0], g1 = g[1];
        acc[0] += xv * g0.x; acc[1] += xv * g0.y; acc[2] += xv * g0.z; acc[3] += xv * g0.w;
        acc[4] += xv * g1.x; acc[5] += xv * g1.y; acc[6] += xv * g1.z; acc[7] += xv * g1.w;
    }
#pragma unroll
    for (int off = 32; off >= 1; off >>= 1)
#pragma unroll
        for (int e = 0; e < 8; ++e)
            acc[e] += __shfl_down(acc[e], off);
    if (lane == 0) {
        float mx = acc[0];
#pragma unroll
        for (int e = 1; e < 8; ++e) mx = fmaxf(mx, acc[e]);
        float p[8]; float s = 0.f;
#pragma unroll
        for (int e = 0; e < 8; ++e) { p[e] = expf(acc[e] - mx); s += p[e]; }
        float inv_s = 1.f / s;
#pragma unroll
        for (int e = 0; e < 8; ++e) p[e] *= inv_s;
        int e1 = 0; float p1 = p[0];
#pragma unroll
        for (int e = 1; e < 8; ++e) if (p[e] > p1) { p1 = p[e]; e1 = e; }
        int e2 = -1; float p2 = -1.f;
#pragma unroll
        for (int e = 0; e < 8; ++e) { if (e == e1) continue; if (p[e] > p2) { p2 = p[e]; e2 = e; } }
        float inv = 1.f / (p1 + p2);
        sel[t * 2 + 0] = e1; sel[t * 2 + 1] = e2;
        selw[t * 2 + 0] = p1 * inv; selw[t * 2 + 1] = p2 * inv;
    }
}

// ---------------- scan: histogram sel -> cnt/off/fill + BOTH tile tables (1 block) ----------
__global__ __launch_bounds__(256) void scan_kernel(const int* __restrict__ sel,
                                                   int* __restrict__ cnt, int* __restrict__ off,
                                                   int* __restrict__ fill,
                                                   int* __restrict__ tileExp, int* __restrict__ tileM0,
                                                   int* __restrict__ tileExpU, int* __restrict__ tileM0U) {
    __shared__ int h[NEXP];
    int tid = threadIdx.x;
    if (tid < NEXP) h[tid] = 0;
    __syncthreads();
    for (int i = tid; i < TOTROWS; i += 256) atomicAdd(&h[sel[i]], 1);
    __syncthreads();
    if (tid == 0) {
        int o = 0;
        for (int e = 0; e < NEXP; ++e) { cnt[e] = h[e]; off[e] = o; o += h[e]; fill[e] = 0; }
        int nt = 0;
        for (int e = 0; e < NEXP; ++e)
            for (int m0 = 0; m0 < h[e]; m0 += 128) { tileExp[nt] = e; tileM0[nt] = m0; nt++; }
        for (int i = nt; i < MAXTILES; ++i) { tileExp[i] = -1; tileM0[i] = 0; }
        int nu = 0;
        for (int e = 0; e < NEXP; ++e)
            for (int m0 = 0; m0 < h[e]; m0 += 256) { tileExpU[nu] = e; tileM0U[nu] = m0; nu++; }
        for (int i = nu; i < UPT; ++i) { tileExpU[i] = -1; tileM0U[i] = 0; }
    }
}

// ---------------- fused scatter+gather: slots + copy x row (bf16) to both expert rows --------
__global__ __launch_bounds__(256) void scatgath_kernel(const int* __restrict__ sel,
                                                       const float* __restrict__ selw,
                                                       const int* __restrict__ off,
                                                       int* __restrict__ fill,
                                                       float* __restrict__ rowWgt,
                                                       int* __restrict__ tokRow,
                                                       const float* __restrict__ x,
                                                       unsigned short* __restrict__ Xg) {
    __shared__ int rs[2];
    int t = blockIdx.x;
    int tid = threadIdx.x;
    if (tid == 0) {
#pragma unroll
        for (int k = 0; k < 2; ++k) {
            int e = sel[t * 2 + k];
            int slot = atomicAdd(&fill[e], 1);
            int r = off[e] + slot;
            rowWgt[r] = selw[t * 2 + k];
            tokRow[t * 2 + k] = r;
            rs[k] = r;
        }
    }
    __syncthreads();
    int r1 = rs[0], r2 = rs[1];
    float4 v = ((const float4*)(x + (size_t)t * H_DIM))[tid];
    ushort4 o;
    o.x = f2b(v.x); o.y = f2b(v.y); o.z = f2b(v.z); o.w = f2b(v.w);
    ((ushort4*)(Xg + (size_t)r1 * H_DIM))[tid] = o;
    ((ushort4*)(Xg + (size_t)r2 * H_DIM))[tid] = o;
}

// ---------------- fused transpose+cvt for all 3 weight tensors ----------------
__global__ __launch_bounds__(256) void transpose_cvt_kernel(
        const float* __restrict__ w_up, const float* __restrict__ w_gate,
        const float* __restrict__ w_down,
        unsigned short* __restrict__ wTu, unsigned short* __restrict__ wTg,
        unsigned short* __restrict__ wTd) {
    __shared__ unsigned short lt[64 * 68];
    int z = blockIdx.z;
    int e = blockIdx.y;
    const float* src; unsigned short* dst; int R, C, tr, tc;
    if (z == 0)      { src = w_up;   dst = wTu; R = H_DIM; C = F_DIM; }
    else if (z == 1) { src = w_gate; dst = wTg; R = H_DIM; C = F_DIM; }
    else             { src = w_down; dst = wTd; R = F_DIM; C = H_DIM; }
    if (R == H_DIM) { tc = blockIdx.x & 31; tr = blockIdx.x >> 5; }
    else            { tc = blockIdx.x & 15; tr = blockIdx.x >> 4; }
    const float* s = src + (size_t)e * H_DIM * F_DIM;
    unsigned short* d = dst + (size_t)e * H_DIM * F_DIM;
    int r0 = tr * 64, c0 = tc * 64;
    int tid = threadIdx.x;
    int fc = tid & 15, row = tid >> 4;
#pragma unroll
    for (int i = 0; i < 4; ++i) {
        int r = row + i * 16;
        float4 v = *(const float4*)(s + (size_t)(r0 + r) * C + c0 + fc * 4);
        lt[(fc * 4 + 0) * 68 + r] = f2b(v.x);
        lt[(fc * 4 + 1) * 68 + r] = f2b(v.y);
        lt[(fc * 4 + 2) * 68 + r] = f2b(v.z);
        lt[(fc * 4 + 3) * 68 + r] = f2b(v.w);
    }
    __syncthreads();
    int ch = tid & 7, cc = tid >> 3;
#pragma unroll
    for (int i = 0; i < 2; ++i) {
        int c = cc + i * 32;
        uint2 lo = *(const uint2*)&lt[c * 68 + ch * 8];
        uint2 hi = *(const uint2*)&lt[c * 68 + ch * 8 + 4];
        uint4 o = make_uint4(lo.x, lo.y, hi.x, hi.y);
        *(uint4*)(d + (size_t)(c0 + c) * R + r0 + ch * 8) = o;
    }
}

// =============== up/gate GEMM: 256x128, BK=32, TRIPLE-buffer, 512 thr / 8 waves (4Mx2N) ======
// Per K-tile: 2 phases of 16 MFMA: {ds_read || gload-issue -> bar -> lgkm(0) -> MFMA -> bar}.
// vmcnt(4) once per tile (stage(t+1)'s 4 loads stay in flight). Stage t+2 into distinct buf.
#define UPG_TILE(VN, B, NB, K2, DOST) do {                                        \
    asm volatile("s_waitcnt vmcnt(" #VN ")" ::: "memory");                        \
    __builtin_amdgcn_s_barrier();                                                 \
    __builtin_amdgcn_sched_barrier(0);                                            \
    bf16x8 af_[4], bb_[4];                                                        \
    _Pragma("unroll") for (int x_ = 0; x_ < 4; ++x_)                              \
        af_[x_] = *(const bf16x8*)&la[B][aIdx[x_]];                               \
    _Pragma("unroll") for (int x_ = 0; x_ < 4; ++x_)                              \
        bb_[x_] = *(const bf16x8*)&lbu[B][bIdx[x_]];                              \
    if (DOST) { gload16(aB + sA0 + (K2), &la[NB][dA0]);                           \
                gload16(aB + sA1 + (K2), &la[NB][dA1]); }                         \
    __builtin_amdgcn_s_barrier();                                                 \
    asm volatile("s_waitcnt lgkmcnt(0)" ::: "memory");                            \
    __builtin_amdgcn_sched_barrier(0);                                            \
    __builtin_amdgcn_s_setprio(1);                                                \
    _Pragma("unroll") for (int i_ = 0; i_ < 4; ++i_)                              \
        _Pragma("unroll") for (int j_ = 0; j_ < 4; ++j_)                          \
            accU[i_][j_] = __builtin_amdgcn_mfma_f32_16x16x32_bf16(af_[i_], bb_[j_], accU[i_][j_], 0, 0, 0); \
    __builtin_amdgcn_s_setprio(0);                                                \
    __builtin_amdgcn_sched_barrier(0);                                            \
    __builtin_amdgcn_s_barrier();                                                 \
    _Pragma("unroll") for (int x_ = 0; x_ < 4; ++x_)                              \
        bb_[x_] = *(const bf16x8*)&lbg[B][bIdx[x_]];                              \
    if (DOST) { gload16(buW + sB + (K2), &lbu[NB][dB]);                           \
                gload16(bgW + sB + (K2), &lbg[NB][dB]); }                         \
    __builtin_amdgcn_s_barrier();                                                 \
    asm volatile("s_waitcnt lgkmcnt(0)" ::: "memory");                            \
    __builtin_amdgcn_sched_barrier(0);                                            \
    __builtin_amdgcn_s_setprio(1);                                                \
    _Pragma("unroll") for (int i_ = 0; i_ < 4; ++i_)                              \
        _Pragma("unroll") for (int j_ = 0; j_ < 4; ++j_)                          \
            accG[i_][j_] = __builtin_amdgcn_mfma_f32_16x16x32_bf16(af_[i_], bb_[j_], accG[i_][j_], 0, 0, 0); \
    __builtin_amdgcn_s_setprio(0);                                                \
    __builtin_amdgcn_sched_barrier(0);                                            \
    __builtin_amdgcn_s_barrier();                                                 \
} while (0)

#define UPG_STAGE_ALL(K2, NB) do {                                                \
    gload16(aB + sA0 + (K2), &la[NB][dA0]);                                       \
    gload16(aB + sA1 + (K2), &la[NB][dA1]);                                       \
    gload16(buW + sB + (K2), &lbu[NB][dB]);                                       \
    gload16(bgW + sB + (K2), &lbg[NB][dB]);                                       \
} while (0)

__global__ __launch_bounds__(512, 2) void gemm_upgate_kernel(
        const unsigned short* __restrict__ Xg,
        const unsigned short* __restrict__ wTu,   // [E][F][H] (k-major)
        const unsigned short* __restrict__ wTg,
        unsigned short* __restrict__ inner,       // [TOTROWS][F]
        const int* __restrict__ tileExpU, const int* __restrict__ tileM0U,
        const int* __restrict__ off, const int* __restrict__ cnt) {
    __shared__ __align__(16) unsigned short la[3][8192];    // 16KB x3 (256x32)
    __shared__ __align__(16) unsigned short lbu[3][4096];   // 8KB x3 (128x32)
    __shared__ __align__(16) unsigned short lbg[3][4096];   // total 96KB -> 1 block/CU
    int bt = blockIdx.y;
    int e = tileExpU[bt];
    if (e < 0) return;
    int m0 = tileM0U[bt];
    int r0 = off[e] + m0;
    int valid = cnt[e] - m0;
    int f0 = blockIdx.x * 128;
    const unsigned short* aB  = Xg + (size_t)r0 * H_DIM;
    const unsigned short* buW = wTu + (size_t)e * F_DIM * H_DIM + (size_t)f0 * H_DIM;
    const unsigned short* bgW = wTg + (size_t)e * F_DIM * H_DIM + (size_t)f0 * H_DIM;
    int tid = threadIdx.x;
    int lane = tid & 63, wid = tid >> 6;   // 8 waves
    int wm = wid >> 1, wn = wid & 1;       // 4M x 2N -> 64x64 per wave
    int l16 = lane & 15, quad = lane >> 4;

    // staging: A 1024 slots (2 its), B 512 slots (1 it); wave-uniform LDS dst.
    int sA0 = swz_src(tid, H_DIM);
    int sA1 = swz_src(512 + tid, H_DIM);
    int sB  = swz_src(tid, H_DIM);
    int dA0 = wid * 512;
    int dA1 = 4096 + wid * 512;
    int dB  = wid * 512;

    int aIdx[4], bIdx[4];
#pragma unroll
    for (int i = 0; i < 4; ++i) aIdx[i] = swz_frag(wm * 64 + i * 16 + l16, quad);
#pragma unroll
    for (int j = 0; j < 4; ++j) bIdx[j] = swz_frag(wn * 64 + j * 16 + l16, quad);

    f32x4 accU[4][4], accG[4][4];
#pragma unroll
    for (int i = 0; i < 4; ++i)
#pragma unroll
        for (int j = 0; j < 4; ++j) { accU[i][j] = (f32x4)0.f; accG[i][j] = (f32x4)0.f; }

    // prologue: tiles 0,1 in flight (8 loads/lane)
    UPG_STAGE_ALL(0, 0);
    UPG_STAGE_ALL(32, 1);

    for (int t = 0; t < 30; t += 3) {     // K = 1024/32 = 32 tiles; stage 2..31 in-loop
        int k2 = (t + 2) * 32;
        UPG_TILE(4, 0, 2, k2, 1);
        UPG_TILE(4, 1, 0, k2 + 32, 1);
        UPG_TILE(4, 2, 1, k2 + 64, 1);
    }
    UPG_TILE(4, 0, 0, 0, 0);   // tile 30 (stage(31) still in flight)
    UPG_TILE(0, 1, 0, 0, 0);   // tile 31 (full drain)

#pragma unroll
    for (int i = 0; i < 4; ++i) {
#pragma unroll
        for (int rr = 0; rr < 4; ++rr) {
            int ml = wm * 64 + i * 16 + quad * 4 + rr;
            if (ml >= valid) continue;
            size_t base = (size_t)(r0 + ml) * F_DIM + f0;
#pragma unroll
            for (int j = 0; j < 4; ++j) {
                float u = accU[i][j][rr];
                float g = accG[i][j][rr];
                float v = u * __builtin_amdgcn_rcpf(1.f + __expf(-u)) * g;   // silu(up)*gate
                inner[base + wn * 64 + j * 16 + l16] = f2b(v);
            }
        }
    }
}

// =============== down GEMM: 128x128, BK=32, TRIPLE-buffer, 256 thr / 4 waves, 3 blocks/CU ===
#define DWN_TILE(VN, B, NB, K2, DOST) do {                                        \
    asm volatile("s_waitcnt vmcnt(" #VN ")" ::: "memory");                        \
    __builtin_amdgcn_s_barrier();                                                 \
    __builtin_amdgcn_sched_barrier(0);                                            \
    bf16x8 af_[4], bw_[4];                                                        \
    _Pragma("unroll") for (int x_ = 0; x_ < 4; ++x_)                              \
        af_[x_] = *(const bf16x8*)&la[B][aIdx[x_]];                               \
    _Pragma("unroll") for (int x_ = 0; x_ < 4; ++x_)                              \
        bw_[x_] = *(const bf16x8*)&lb[B][bIdx[x_]];                               \
    if (DOST) { gload16(aB + s0 + (K2), &la[NB][d0]);                             \
                gload16(aB + s1 + (K2), &la[NB][d1]);                             \
                gload16(bp + s0 + (K2), &lb[NB][d0]);                             \
                gload16(bp + s1 + (K2), &lb[NB][d1]); }                           \
    __builtin_amdgcn_s_barrier();                                                 \
    asm volatile("s_waitcnt lgkmcnt(0)" ::: "memory");                            \
    __builtin_amdgcn_sched_barrier(0);                                            \
    __builtin_amdgcn_s_setprio(1);                                                \
    _Pragma("unroll") for (int i_ = 0; i_ < 4; ++i_)                              \
        _Pragma("unroll") for (int j_ = 0; j_ < 4; ++j_)                          \
            acc[i_][j_] = __builtin_amdgcn_mfma_f32_16x16x32_bf16(af_[i_], bw_[j_], acc[i_][j_], 0, 0, 0); \
    __builtin_amdgcn_s_setprio(0);                                                \
    __builtin_amdgcn_sched_barrier(0);                                            \
    __builtin_amdgcn_s_barrier();                                                 \
} while (0)

#define DWN_STAGE_ALL(K2, NB) do {                                                \
    gload16(aB + s0 + (K2), &la[NB][d0]);                                         \
    gload16(aB + s1 + (K2), &la[NB][d1]);                                         \
    gload16(bp + s0 + (K2), &lb[NB][d0]);                                         \
    gload16(bp + s1 + (K2), &lb[NB][d1]);                                         \
} while (0)

__global__ __launch_bounds__(256, 3) void gemm_down_kernel(
        const unsigned short* __restrict__ inner,  // [TOTROWS][F]
        const unsigned short* __restrict__ wTd,    // [E][H][F] (k-major)
        float* __restrict__ part,                  // [TOTROWS][H]
        const int* __restrict__ tileExp, const int* __restrict__ tileM0,
        const int* __restrict__ off, const int* __restrict__ cnt,
        const float* __restrict__ rowWgt) {
    __shared__ __align__(16) unsigned short la[3][4096];   // 8KB x3 (128x32)
    __shared__ __align__(16) unsigned short lb[3][4096];   // 48KB total -> 3 blocks/CU
    int bt = blockIdx.y;
    int e = tileExp[bt];
    if (e < 0) return;
    int m0 = tileM0[bt];
    int r0 = off[e] + m0;
    int valid = cnt[e] - m0;
    int h0 = blockIdx.x * 128;
    const unsigned short* aB = inner + (size_t)r0 * F_DIM;
    const unsigned short* bp = wTd + (size_t)e * H_DIM * F_DIM + (size_t)h0 * F_DIM;
    int tid = threadIdx.x;
    int lane = tid & 63, wid = tid >> 6;   // 4 waves
    int wm = wid >> 1, wn = wid & 1;       // 2M x 2N -> 64x64 per wave
    int l16 = lane & 15, quad = lane >> 4;

    // staging: A/B each 512 slots (2 its x 256 thr)
    int s0 = swz_src(tid, F_DIM);
    int s1 = swz_src(256 + tid, F_DIM);
    int d0 = wid * 512;
    int d1 = 2048 + wid * 512;

    int aIdx[4], bIdx[4];
#pragma unroll
    for (int i = 0; i < 4; ++i) aIdx[i] = swz_frag(wm * 64 + i * 16 + l16, quad);
#pragma unroll
    for (int j = 0; j < 4; ++j) bIdx[j] = swz_frag(wn * 64 + j * 16 + l16, quad);

    f32x4 acc[4][4];
#pragma unroll
    for (int i = 0; i < 4; ++i)
#pragma unroll
        for (int j = 0; j < 4; ++j) acc[i][j] = (f32x4)0.f;

    DWN_STAGE_ALL(0, 0);
    DWN_STAGE_ALL(32, 1);

    for (int t = 0; t < 60; t += 3) {      // K = 2048/32 = 64 tiles; stage 2..61 in-loop
        int k2 = (t + 2) * 32;
        DWN_TILE(4, 0, 2, k2, 1);
        DWN_TILE(4, 1, 0, k2 + 32, 1);
        DWN_TILE(4, 2, 1, k2 + 64, 1);
    }
    DWN_TILE(4, 0, 2, 62 * 32, 1);   // tile 60 stages 62
    DWN_TILE(4, 1, 0, 63 * 32, 1);   // tile 61 stages 63
    DWN_TILE(4, 2, 0, 0, 0);         // tile 62
    DWN_TILE(0, 0, 0, 0, 0);         // tile 63 (full drain)

#pragma unroll
    for (int i = 0; i < 4; ++i) {
#pragma unroll
        for (int rr = 0; rr < 4; ++rr) {
            int ml = wm * 64 + i * 16 + quad * 4 + rr;
            if (ml >= valid) continue;
            int gr = r0 + ml;
            float w = rowWgt[gr];
            float* orow = part + (size_t)gr * H_DIM + h0;
#pragma unroll
            for (int j = 0; j < 4; ++j)
                orow[wn * 64 + j * 16 + l16] = w * acc[i][j][rr];
        }
    }
}

// ---------------- combine: out[t] = part[r1] + part[r2] ----------------
__global__ __launch_bounds__(256) void combine_kernel(const float* __restrict__ part,
                                                      const int* __restrict__ tokRow,
                                                      float* __restrict__ out) {
    int t = blockIdx.x;
    int r1 = tokRow[t * 2 + 0], r2 = tokRow[t * 2 + 1];
    int i = threadIdx.x;
    float4 a = ((const float4*)(part + (size_t)r1 * H_DIM))[i];
    float4 b = ((const float4*)(part + (size_t)r2 * H_DIM))[i];
    float4 o;
    o.x = a.x + b.x; o.y = a.y + b.y; o.z = a.z + b.z; o.w = a.w + b.w;
    ((float4*)(out + (size_t)t * H_DIM))[i] = o;
}

extern "C" void kernel_launch(void* const* d_in, const int* in_sizes, int n_in,
                              void* d_out, int out_size, void* d_ws, size_t ws_size,
                              hipStream_t stream) {
    const float* x      = (const float*)d_in[0];
    const float* gw     = (const float*)d_in[1];
    const float* w_up   = (const float*)d_in[2];
    const float* w_gate = (const float*)d_in[3];
    const float* w_down = (const float*)d_in[4];
    float* out = (float*)d_out;

    char* ws = (char*)d_ws;
    size_t o = 0;
    unsigned short* wTu = (unsigned short*)(ws + o); o += (size_t)NEXP * F_DIM * H_DIM * 2;
    unsigned short* wTg = (unsigned short*)(ws + o); o += (size_t)NEXP * F_DIM * H_DIM * 2;
    unsigned short* wTd = (unsigned short*)(ws + o); o += (size_t)NEXP * H_DIM * F_DIM * 2;
    unsigned short* Xg  = (unsigned short*)(ws + o); o += (size_t)TOTROWS * H_DIM * 2;
    unsigned short* inner = (unsigned short*)(ws + o); o += (size_t)TOTROWS * F_DIM * 2;
    o += 2 * 1024 * 1024;  // pad: tail-row overreads stay in ws
    float* rowWgt = (float*)(ws + o); o += TOTROWS * 4;
    int*   tokRow = (int*)(ws + o);   o += T_TOK * 2 * 4;
    int*   sel    = (int*)(ws + o);   o += T_TOK * 2 * 4;
    float* selw   = (float*)(ws + o); o += T_TOK * 2 * 4;
    int*   cnt    = (int*)(ws + o);   o += 8 * 4;
    int*   fill   = (int*)(ws + o);   o += 8 * 4;
    int*   off_   = (int*)(ws + o);   o += 8 * 4;
    int*   tileExp = (int*)(ws + o);  o += MAXTILES * 4;
    int*   tileM0  = (int*)(ws + o);  o += MAXTILES * 4;
    int*   tileExpU = (int*)(ws + o); o += UPT * 4;
    int*   tileM0U  = (int*)(ws + o); o += UPT * 4;
    // part[TOTROWS][H] fp32 aliases wTu+wTg (dead after gemm_upgate; stream-serial)
    float* part = (float*)wTu;

    router_kernel<<<T_TOK / 4, 256, 0, stream>>>(x, gw, sel, selw);
    scan_kernel<<<1, 256, 0, stream>>>(sel, cnt, off_, fill, tileExp, tileM0, tileExpU, tileM0U);
    scatgath_kernel<<<T_TOK, 256, 0, stream>>>(sel, selw, off_, fill, rowWgt, tokRow, x, Xg);
    transpose_cvt_kernel<<<dim3(512, NEXP, 3), 256, 0, stream>>>(w_up, w_gate, w_down, wTu, wTg, wTd);
    gemm_upgate_kernel<<<dim3(F_DIM / 128, UPT), 512, 0, stream>>>(Xg, wTu, wTg, inner, tileExpU, tileM0U, off_, cnt);
    gemm_down_kernel<<<dim3(H_DIM / 128, 72), 256, 0, stream>>>(inner, wTd, part, tileExp, tileM0, off_, cnt, rowWgt);
    combine_kernel<<<T_TOK, 256, 0, stream>>>(part, tokRow, out);
}

// Round 5
// 502.010 us; speedup vs baseline: 1.2772x; 1.0274x over previous
//
#include <hip/hip_runtime.h>
#include <hip/hip_bf16.h>

typedef __bf16 bf16x8 __attribute__((ext_vector_type(8)));
typedef float f32x4 __attribute__((ext_vector_type(4)));

#define T_TOK 4096
#define H_DIM 1024
#define F_DIM 2048
#define NEXP 8
#define TOTROWS 8192   // T_TOK * TOP_K, always exact (top-2 distinct experts)
#define MAXTILES 80    // 128-row tiles

__device__ inline unsigned short f2b(float f) {
    unsigned int u = __float_as_uint(f);
    unsigned int r = (u + 0x7fffu + ((u >> 16) & 1u)) >> 16;
    return (unsigned short)r;
}

// ---------------- router: logits -> softmax -> top2 -> renorm (4 tokens/block, no atomics) ----
__global__ __launch_bounds__(256) void router_kernel(const float* __restrict__ x,
                                                     const float* __restrict__ gw,
                                                     int* __restrict__ sel, float* __restrict__ selw) {
    int t = blockIdx.x * 4 + (threadIdx.x >> 6);
    int lane = threadIdx.x & 63;
    float acc[8] = {0.f,0.f,0.f,0.f,0.f,0.f,0.f,0.f};
    const float* xr = x + (size_t)t * H_DIM;
    for (int h = lane; h < H_DIM; h += 64) {
        float xv = xr[h];
        const float4* g = (const float4*)(gw + h * 8);
        float4 g0 = g[0], g1 = g[1];
        acc[0] += xv * g0.x; acc[1] += xv * g0.y; acc[2] += xv * g0.z; acc[3] += xv * g0.w;
        acc[4] += xv * g1.x; acc[5] += xv * g1.y; acc[6] += xv * g1.z; acc[7] += xv * g1.w;
    }
#pragma unroll
    for (int off = 32; off >= 1; off >>= 1)
#pragma unroll
        for (int e = 0; e < 8; ++e)
            acc[e] += __shfl_down(acc[e], off);
    if (lane == 0) {
        float mx = acc[0];
#pragma unroll
        for (int e = 1; e < 8; ++e) mx = fmaxf(mx, acc[e]);
        float p[8]; float s = 0.f;
#pragma unroll
        for (int e = 0; e < 8; ++e) { p[e] = expf(acc[e] - mx); s += p[e]; }
        float inv_s = 1.f / s;
#pragma unroll
        for (int e = 0; e < 8; ++e) p[e] *= inv_s;
        int e1 = 0; float p1 = p[0];
#pragma unroll
        for (int e = 1; e < 8; ++e) if (p[e] > p1) { p1 = p[e]; e1 = e; }
        int e2 = -1; float p2 = -1.f;
#pragma unroll
        for (int e = 0; e < 8; ++e) { if (e == e1) continue; if (p[e] > p2) { p2 = p[e]; e2 = e; } }
        float inv = 1.f / (p1 + p2);
        sel[t * 2 + 0] = e1; sel[t * 2 + 1] = e2;
        selw[t * 2 + 0] = p1 * inv; selw[t * 2 + 1] = p2 * inv;
    }
}

// ---------------- scan: histogram sel -> cnt/off/fill/tile table (1 block) ----------------
__global__ __launch_bounds__(256) void scan_kernel(const int* __restrict__ sel,
                                                   int* __restrict__ cnt, int* __restrict__ off,
                                                   int* __restrict__ fill,
                                                   int* __restrict__ tileExp, int* __restrict__ tileM0) {
    __shared__ int h[NEXP];
    int tid = threadIdx.x;
    if (tid < NEXP) h[tid] = 0;
    __syncthreads();
    for (int i = tid; i < TOTROWS; i += 256) atomicAdd(&h[sel[i]], 1);
    __syncthreads();
    if (tid == 0) {
        int o = 0;
        for (int e = 0; e < NEXP; ++e) { cnt[e] = h[e]; off[e] = o; o += h[e]; fill[e] = 0; }
        int nt = 0;
        for (int e = 0; e < NEXP; ++e)
            for (int m0 = 0; m0 < h[e]; m0 += 128) { tileExp[nt] = e; tileM0[nt] = m0; nt++; }
        for (int i = nt; i < MAXTILES; ++i) { tileExp[i] = -1; tileM0[i] = 0; }
    }
}

// ---------------- fused scatter+gather: slots + copy x row (bf16) to both expert rows --------
__global__ __launch_bounds__(256) void scatgath_kernel(const int* __restrict__ sel,
                                                       const float* __restrict__ selw,
                                                       const int* __restrict__ off,
                                                       int* __restrict__ fill,
                                                       float* __restrict__ rowWgt,
                                                       int* __restrict__ tokRow,
                                                       const float* __restrict__ x,
                                                       unsigned short* __restrict__ Xg) {
    __shared__ int rs[2];
    int t = blockIdx.x;
    int tid = threadIdx.x;
    if (tid == 0) {
#pragma unroll
        for (int k = 0; k < 2; ++k) {
            int e = sel[t * 2 + k];
            int slot = atomicAdd(&fill[e], 1);
            int r = off[e] + slot;
            rowWgt[r] = selw[t * 2 + k];
            tokRow[t * 2 + k] = r;
            rs[k] = r;
        }
    }
    __syncthreads();
    int r1 = rs[0], r2 = rs[1];
    float4 v = ((const float4*)(x + (size_t)t * H_DIM))[tid];
    ushort4 o;
    o.x = f2b(v.x); o.y = f2b(v.y); o.z = f2b(v.z); o.w = f2b(v.w);
    ((ushort4*)(Xg + (size_t)r1 * H_DIM))[tid] = o;
    ((ushort4*)(Xg + (size_t)r2 * H_DIM))[tid] = o;
}

// ---------------- fused transpose+cvt for all 3 weight tensors ----------------
__global__ __launch_bounds__(256) void transpose_cvt_kernel(
        const float* __restrict__ w_up, const float* __restrict__ w_gate,
        const float* __restrict__ w_down,
        unsigned short* __restrict__ wTu, unsigned short* __restrict__ wTg,
        unsigned short* __restrict__ wTd) {
    __shared__ unsigned short lt[64 * 68];
    int z = blockIdx.z;
    int e = blockIdx.y;
    const float* src; unsigned short* dst; int R, C, tr, tc;
    if (z == 0)      { src = w_up;   dst = wTu; R = H_DIM; C = F_DIM; }
    else if (z == 1) { src = w_gate; dst = wTg; R = H_DIM; C = F_DIM; }
    else             { src = w_down; dst = wTd; R = F_DIM; C = H_DIM; }
    if (R == H_DIM) { tc = blockIdx.x & 31; tr = blockIdx.x >> 5; }
    else            { tc = blockIdx.x & 15; tr = blockIdx.x >> 4; }
    const float* s = src + (size_t)e * H_DIM * F_DIM;
    unsigned short* d = dst + (size_t)e * H_DIM * F_DIM;
    int r0 = tr * 64, c0 = tc * 64;
    int tid = threadIdx.x;
    int fc = tid & 15, row = tid >> 4;
#pragma unroll
    for (int i = 0; i < 4; ++i) {
        int r = row + i * 16;
        float4 v = *(const float4*)(s + (size_t)(r0 + r) * C + c0 + fc * 4);
        lt[(fc * 4 + 0) * 68 + r] = f2b(v.x);
        lt[(fc * 4 + 1) * 68 + r] = f2b(v.y);
        lt[(fc * 4 + 2) * 68 + r] = f2b(v.z);
        lt[(fc * 4 + 3) * 68 + r] = f2b(v.w);
    }
    __syncthreads();
    int ch = tid & 7, cc = tid >> 3;
#pragma unroll
    for (int i = 0; i < 2; ++i) {
        int c = cc + i * 32;
        uint2 lo = *(const uint2*)&lt[c * 68 + ch * 8];
        uint2 hi = *(const uint2*)&lt[c * 68 + ch * 8 + 4];
        uint4 o = make_uint4(lo.x, lo.y, hi.x, hi.y);
        *(uint4*)(d + (size_t)(c0 + c) * R + r0 + ch * 8) = o;
    }
}

// =============== up/gate GEMM: 128x128, BK=32, REG-staged (T14), 256 thr / 4 waves ===========
// Per K-tile (one barrier): {12 ds_read frags | 6 ds_write (tile t+1, regs loaded 2 tiles
// ago -> compiler emits counted vmcnt) | 6 global_load (tile t+2 -> regs) | 32 MFMA |
// lgkm(0); s_barrier}.  No global_load_lds => no compiler vmcnt(0) drain at barriers.
// LDS tile [128 rows][32 k], 16B chunk at (row, q) stored at q^(row&3): fragment reads
// (16 lanes same quad, rows r..r+15) spread 8 lanes/bank-group = conflict-free minimum.
__global__ __launch_bounds__(256, 2) void gemm_upgate_kernel(
        const unsigned short* __restrict__ Xg,
        const unsigned short* __restrict__ wTu,   // [E][F][H] (k-major)
        const unsigned short* __restrict__ wTg,
        unsigned short* __restrict__ inner,       // [TOTROWS][F]
        const int* __restrict__ tileExp, const int* __restrict__ tileM0,
        const int* __restrict__ off, const int* __restrict__ cnt) {
    __shared__ __align__(16) unsigned short la[2][4096];    // 8KB x2 (128x32)
    __shared__ __align__(16) unsigned short lbu[2][4096];
    __shared__ __align__(16) unsigned short lbg[2][4096];   // 48KB total -> 2 blocks/CU (VGPR-capped)
    int bt = blockIdx.y;
    int e = tileExp[bt];
    if (e < 0) return;
    int m0 = tileM0[bt];
    int r0 = off[e] + m0;
    int valid = cnt[e] - m0;
    int f0 = blockIdx.x * 128;
    const unsigned short* aB  = Xg + (size_t)r0 * H_DIM;
    const unsigned short* buW = wTu + (size_t)e * F_DIM * H_DIM + (size_t)f0 * H_DIM;
    const unsigned short* bgW = wTg + (size_t)e * F_DIM * H_DIM + (size_t)f0 * H_DIM;
    int tid = threadIdx.x;
    int lane = tid & 63, wid = tid >> 6;   // 4 waves
    int wm = wid >> 1, wn = wid & 1;       // 2M x 2N -> 64x64 per wave (dual U+G acc)
    int l16 = lane & 15, quad = lane >> 4;

    // staging map: 512 chunks/tile; thread owns chunks tid and tid+256 (all 3 arrays share it)
    int rA0 = tid >> 2, rA1 = rA0 + 64;
    int s0 = rA0 * H_DIM + (tid & 3) * 8;
    int s1 = rA1 * H_DIM + (tid & 3) * 8;
    int d0 = rA0 * 32 + (((tid & 3) ^ (rA0 & 3)) << 3);
    int d1 = rA1 * 32 + (((tid & 3) ^ (rA1 & 3)) << 3);

    // fragment LDS indices (ushort units)
    int aIdx[4], bIdx[4];
#pragma unroll
    for (int i = 0; i < 4; ++i) {
        int lr = wm * 64 + i * 16 + l16;
        aIdx[i] = lr * 32 + ((quad ^ (lr & 3)) << 3);
    }
#pragma unroll
    for (int j = 0; j < 4; ++j) {
        int lr = wn * 64 + j * 16 + l16;
        bIdx[j] = lr * 32 + ((quad ^ (lr & 3)) << 3);
    }

    f32x4 accU[4][4], accG[4][4];
#pragma unroll
    for (int i = 0; i < 4; ++i)
#pragma unroll
        for (int j = 0; j < 4; ++j) { accU[i][j] = (f32x4)0.f; accG[i][j] = (f32x4)0.f; }

    uint4 va0, va1, vu0, vu1, vg0, vg1;   // staging regs (one tile)

#define UPG_LOAD(K0) do {                                        \
    va0 = *(const uint4*)(aB + s0 + (K0));                       \
    va1 = *(const uint4*)(aB + s1 + (K0));                       \
    vu0 = *(const uint4*)(buW + s0 + (K0));                      \
    vu1 = *(const uint4*)(buW + s1 + (K0));                      \
    vg0 = *(const uint4*)(bgW + s0 + (K0));                      \
    vg1 = *(const uint4*)(bgW + s1 + (K0));                      \
} while (0)
#define UPG_WRITE(NB) do {                                       \
    *(uint4*)&la[NB][d0]  = va0;  *(uint4*)&la[NB][d1]  = va1;   \
    *(uint4*)&lbu[NB][d0] = vu0;  *(uint4*)&lbu[NB][d1] = vu1;   \
    *(uint4*)&lbg[NB][d0] = vg0;  *(uint4*)&lbg[NB][d1] = vg1;   \
} while (0)

    // prologue: tile0 -> LDS buf0; tile1 -> regs
    UPG_LOAD(0);
    UPG_WRITE(0);
    UPG_LOAD(32);
    asm volatile("s_waitcnt lgkmcnt(0)" ::: "memory");
    __builtin_amdgcn_s_barrier();
    __builtin_amdgcn_sched_barrier(0);

    for (int t = 0; t < 32; ++t) {        // K = 1024/32 = 32 tiles
        int cur = t & 1, nxt = cur ^ 1;
        const unsigned short* lac = la[cur];
        const unsigned short* luc = lbu[cur];
        const unsigned short* lgc = lbg[cur];
        bf16x8 af[4], bu[4], bg[4];
#pragma unroll
        for (int i = 0; i < 4; ++i) af[i] = *(const bf16x8*)(lac + aIdx[i]);
#pragma unroll
        for (int j = 0; j < 4; ++j) {
            bu[j] = *(const bf16x8*)(luc + bIdx[j]);
            bg[j] = *(const bf16x8*)(lgc + bIdx[j]);
        }
        if (t < 31) UPG_WRITE(nxt);          // publish tile t+1 (regs -> LDS)
        if (t < 30) UPG_LOAD((t + 2) * 32);  // prefetch tile t+2 (global -> regs)
        __builtin_amdgcn_s_setprio(1);
#pragma unroll
        for (int i = 0; i < 4; ++i)
#pragma unroll
            for (int j = 0; j < 4; ++j) {
                accU[i][j] = __builtin_amdgcn_mfma_f32_16x16x32_bf16(af[i], bu[j], accU[i][j], 0, 0, 0);
                accG[i][j] = __builtin_amdgcn_mfma_f32_16x16x32_bf16(af[i], bg[j], accG[i][j], 0, 0, 0);
            }
        __builtin_amdgcn_s_setprio(0);
        asm volatile("s_waitcnt lgkmcnt(0)" ::: "memory");   // ds_writes drained
        __builtin_amdgcn_s_barrier();
        __builtin_amdgcn_sched_barrier(0);
    }
#undef UPG_LOAD
#undef UPG_WRITE

#pragma unroll
    for (int i = 0; i < 4; ++i) {
#pragma unroll
        for (int rr = 0; rr < 4; ++rr) {
            int ml = wm * 64 + i * 16 + quad * 4 + rr;
            if (ml >= valid) continue;
            size_t base = (size_t)(r0 + ml) * F_DIM + f0;
#pragma unroll
            for (int j = 0; j < 4; ++j) {
                float u = accU[i][j][rr];
                float g = accG[i][j][rr];
                float v = u * __builtin_amdgcn_rcpf(1.f + __expf(-u)) * g;   // silu(up)*gate
                inner[base + wn * 64 + j * 16 + l16] = f2b(v);
            }
        }
    }
}

// =============== down GEMM: 128x128, BK=32, REG-staged, 256 thr / 4 waves, 3 blocks/CU =======
__global__ __launch_bounds__(256, 3) void gemm_down_kernel(
        const unsigned short* __restrict__ inner,  // [TOTROWS][F]
        const unsigned short* __restrict__ wTd,    // [E][H][F] (k-major)
        float* __restrict__ part,                  // [TOTROWS][H]
        const int* __restrict__ tileExp, const int* __restrict__ tileM0,
        const int* __restrict__ off, const int* __restrict__ cnt,
        const float* __restrict__ rowWgt) {
    __shared__ __align__(16) unsigned short la[2][4096];   // 8KB x2 (128x32)
    __shared__ __align__(16) unsigned short lb[2][4096];   // 32KB total -> 3 blocks/CU
    int bt = blockIdx.y;
    int e = tileExp[bt];
    if (e < 0) return;
    int m0 = tileM0[bt];
    int r0 = off[e] + m0;
    int valid = cnt[e] - m0;
    int h0 = blockIdx.x * 128;
    const unsigned short* aB = inner + (size_t)r0 * F_DIM;
    const unsigned short* bp = wTd + (size_t)e * H_DIM * F_DIM + (size_t)h0 * F_DIM;
    int tid = threadIdx.x;
    int lane = tid & 63, wid = tid >> 6;   // 4 waves
    int wm = wid >> 1, wn = wid & 1;       // 2M x 2N -> 64x64 per wave
    int l16 = lane & 15, quad = lane >> 4;

    int rA0 = tid >> 2, rA1 = rA0 + 64;
    int s0 = rA0 * F_DIM + (tid & 3) * 8;
    int s1 = rA1 * F_DIM + (tid & 3) * 8;
    int d0 = rA0 * 32 + (((tid & 3) ^ (rA0 & 3)) << 3);
    int d1 = rA1 * 32 + (((tid & 3) ^ (rA1 & 3)) << 3);

    int aIdx[4], bIdx[4];
#pragma unroll
    for (int i = 0; i < 4; ++i) {
        int lr = wm * 64 + i * 16 + l16;
        aIdx[i] = lr * 32 + ((quad ^ (lr & 3)) << 3);
    }
#pragma unroll
    for (int j = 0; j < 4; ++j) {
        int lr = wn * 64 + j * 16 + l16;
        bIdx[j] = lr * 32 + ((quad ^ (lr & 3)) << 3);
    }

    f32x4 acc[4][4];
#pragma unroll
    for (int i = 0; i < 4; ++i)
#pragma unroll
        for (int j = 0; j < 4; ++j) acc[i][j] = (f32x4)0.f;

    uint4 va0, va1, vb0, vb1;

#define DWN_LOAD(K0) do {                                        \
    va0 = *(const uint4*)(aB + s0 + (K0));                       \
    va1 = *(const uint4*)(aB + s1 + (K0));                       \
    vb0 = *(const uint4*)(bp + s0 + (K0));                       \
    vb1 = *(const uint4*)(bp + s1 + (K0));                       \
} while (0)
#define DWN_WRITE(NB) do {                                       \
    *(uint4*)&la[NB][d0] = va0;  *(uint4*)&la[NB][d1] = va1;     \
    *(uint4*)&lb[NB][d0] = vb0;  *(uint4*)&lb[NB][d1] = vb1;     \
} while (0)

    DWN_LOAD(0);
    DWN_WRITE(0);
    DWN_LOAD(32);
    asm volatile("s_waitcnt lgkmcnt(0)" ::: "memory");
    __builtin_amdgcn_s_barrier();
    __builtin_amdgcn_sched_barrier(0);

    for (int t = 0; t < 64; ++t) {        // K = 2048/32 = 64 tiles
        int cur = t & 1, nxt = cur ^ 1;
        const unsigned short* lac = la[cur];
        const unsigned short* lbc = lb[cur];
        bf16x8 af[4], bw[4];
#pragma unroll
        for (int i = 0; i < 4; ++i) af[i] = *(const bf16x8*)(lac + aIdx[i]);
#pragma unroll
        for (int j = 0; j < 4; ++j) bw[j] = *(const bf16x8*)(lbc + bIdx[j]);
        if (t < 63) DWN_WRITE(nxt);
        if (t < 62) DWN_LOAD((t + 2) * 32);
        __builtin_amdgcn_s_setprio(1);
#pragma unroll
        for (int i = 0; i < 4; ++i)
#pragma unroll
            for (int j = 0; j < 4; ++j)
                acc[i][j] = __builtin_amdgcn_mfma_f32_16x16x32_bf16(af[i], bw[j], acc[i][j], 0, 0, 0);
        __builtin_amdgcn_s_setprio(0);
        asm volatile("s_waitcnt lgkmcnt(0)" ::: "memory");
        __builtin_amdgcn_s_barrier();
        __builtin_amdgcn_sched_barrier(0);
    }
#undef DWN_LOAD
#undef DWN_WRITE

#pragma unroll
    for (int i = 0; i < 4; ++i) {
#pragma unroll
        for (int rr = 0; rr < 4; ++rr) {
            int ml = wm * 64 + i * 16 + quad * 4 + rr;
            if (ml >= valid) continue;
            int gr = r0 + ml;
            float w = rowWgt[gr];
            float* orow = part + (size_t)gr * H_DIM + h0;
#pragma unroll
            for (int j = 0; j < 4; ++j)
                orow[wn * 64 + j * 16 + l16] = w * acc[i][j][rr];
        }
    }
}

// ---------------- combine: out[t] = part[r1] + part[r2] ----------------
__global__ __launch_bounds__(256) void combine_kernel(const float* __restrict__ part,
                                                      const int* __restrict__ tokRow,
                                                      float* __restrict__ out) {
    int t = blockIdx.x;
    int r1 = tokRow[t * 2 + 0], r2 = tokRow[t * 2 + 1];
    int i = threadIdx.x;
    float4 a = ((const float4*)(part + (size_t)r1 * H_DIM))[i];
    float4 b = ((const float4*)(part + (size_t)r2 * H_DIM))[i];
    float4 o;
    o.x = a.x + b.x; o.y = a.y + b.y; o.z = a.z + b.z; o.w = a.w + b.w;
    ((float4*)(out + (size_t)t * H_DIM))[i] = o;
}

extern "C" void kernel_launch(void* const* d_in, const int* in_sizes, int n_in,
                              void* d_out, int out_size, void* d_ws, size_t ws_size,
                              hipStream_t stream) {
    const float* x      = (const float*)d_in[0];
    const float* gw     = (const float*)d_in[1];
    const float* w_up   = (const float*)d_in[2];
    const float* w_gate = (const float*)d_in[3];
    const float* w_down = (const float*)d_in[4];
    float* out = (float*)d_out;

    char* ws = (char*)d_ws;
    size_t o = 0;
    unsigned short* wTu = (unsigned short*)(ws + o); o += (size_t)NEXP * F_DIM * H_DIM * 2;
    unsigned short* wTg = (unsigned short*)(ws + o); o += (size_t)NEXP * F_DIM * H_DIM * 2;
    unsigned short* wTd = (unsigned short*)(ws + o); o += (size_t)NEXP * H_DIM * F_DIM * 2;
    unsigned short* Xg  = (unsigned short*)(ws + o); o += (size_t)TOTROWS * H_DIM * 2;
    unsigned short* inner = (unsigned short*)(ws + o); o += (size_t)TOTROWS * F_DIM * 2;
    o += 2 * 1024 * 1024;  // pad: tail-row overreads stay in ws
    float* rowWgt = (float*)(ws + o); o += TOTROWS * 4;
    int*   tokRow = (int*)(ws + o);   o += T_TOK * 2 * 4;
    int*   sel    = (int*)(ws + o);   o += T_TOK * 2 * 4;
    float* selw   = (float*)(ws + o); o += T_TOK * 2 * 4;
    int*   cnt    = (int*)(ws + o);   o += 8 * 4;
    int*   fill   = (int*)(ws + o);   o += 8 * 4;
    int*   off_   = (int*)(ws + o);   o += 8 * 4;
    int*   tileExp = (int*)(ws + o);  o += MAXTILES * 4;
    int*   tileM0  = (int*)(ws + o);  o += MAXTILES * 4;
    // part[TOTROWS][H] fp32 aliases wTu+wTg (dead after gemm_upgate; stream-serial)
    float* part = (float*)wTu;

    router_kernel<<<T_TOK / 4, 256, 0, stream>>>(x, gw, sel, selw);
    scan_kernel<<<1, 256, 0, stream>>>(sel, cnt, off_, fill, tileExp, tileM0);
    scatgath_kernel<<<T_TOK, 256, 0, stream>>>(sel, selw, off_, fill, rowWgt, tokRow, x, Xg);
    transpose_cvt_kernel<<<dim3(512, NEXP, 3), 256, 0, stream>>>(w_up, w_gate, w_down, wTu, wTg, wTd);
    gemm_upgate_kernel<<<dim3(F_DIM / 128, 72), 256, 0, stream>>>(Xg, wTu, wTg, inner, tileExp, tileM0, off_, cnt);
    gemm_down_kernel<<<dim3(H_DIM / 128, 72), 256, 0, stream>>>(inner, wTd, part, tileExp, tileM0, off_, cnt, rowWgt);
    combine_kernel<<<T_TOK, 256, 0, stream>>>(part, tokRow, out);
}

// Round 7
// 446.720 us; speedup vs baseline: 1.4353x; 1.1238x over previous
//
#include <hip/hip_runtime.h>
#include <hip/hip_bf16.h>

typedef __bf16 bf16x8 __attribute__((ext_vector_type(8)));
typedef float f32x4 __attribute__((ext_vector_type(4)));

#define T_TOK 4096
#define H_DIM 1024
#define F_DIM 2048
#define NEXP 8
#define TOTROWS 8192   // T_TOK * TOP_K, always exact (top-2 distinct experts)
#define MAXTILES 80    // 128-row tiles

__device__ inline unsigned short f2b(float f) {
    unsigned int u = __float_as_uint(f);
    unsigned int r = (u + 0x7fffu + ((u >> 16) & 1u)) >> 16;
    return (unsigned short)r;
}

// ---------------- router: logits -> softmax -> top2 -> renorm (4 tokens/block, no atomics) ----
__global__ __launch_bounds__(256) void router_kernel(const float* __restrict__ x,
                                                     const float* __restrict__ gw,
                                                     int* __restrict__ sel, float* __restrict__ selw) {
    int t = blockIdx.x * 4 + (threadIdx.x >> 6);
    int lane = threadIdx.x & 63;
    float acc[8] = {0.f,0.f,0.f,0.f,0.f,0.f,0.f,0.f};
    const float* xr = x + (size_t)t * H_DIM;
    for (int h = lane; h < H_DIM; h += 64) {
        float xv = xr[h];
        const float4* g = (const float4*)(gw + h * 8);
        float4 g0 = g[0], g1 = g[1];
        acc[0] += xv * g0.x; acc[1] += xv * g0.y; acc[2] += xv * g0.z; acc[3] += xv * g0.w;
        acc[4] += xv * g1.x; acc[5] += xv * g1.y; acc[6] += xv * g1.z; acc[7] += xv * g1.w;
    }
#pragma unroll
    for (int off = 32; off >= 1; off >>= 1)
#pragma unroll
        for (int e = 0; e < 8; ++e)
            acc[e] += __shfl_down(acc[e], off);
    if (lane == 0) {
        float mx = acc[0];
#pragma unroll
        for (int e = 1; e < 8; ++e) mx = fmaxf(mx, acc[e]);
        float p[8]; float s = 0.f;
#pragma unroll
        for (int e = 0; e < 8; ++e) { p[e] = expf(acc[e] - mx); s += p[e]; }
        float inv_s = 1.f / s;
#pragma unroll
        for (int e = 0; e < 8; ++e) p[e] *= inv_s;
        int e1 = 0; float p1 = p[0];
#pragma unroll
        for (int e = 1; e < 8; ++e) if (p[e] > p1) { p1 = p[e]; e1 = e; }
        int e2 = -1; float p2 = -1.f;
#pragma unroll
        for (int e = 0; e < 8; ++e) { if (e == e1) continue; if (p[e] > p2) { p2 = p[e]; e2 = e; } }
        float inv = 1.f / (p1 + p2);
        sel[t * 2 + 0] = e1; sel[t * 2 + 1] = e2;
        selw[t * 2 + 0] = p1 * inv; selw[t * 2 + 1] = p2 * inv;
    }
}

// ---------------- scan: histogram sel -> cnt/off/fill/tile table (1 block) ----------------
__global__ __launch_bounds__(256) void scan_kernel(const int* __restrict__ sel,
                                                   int* __restrict__ cnt, int* __restrict__ off,
                                                   int* __restrict__ fill,
                                                   int* __restrict__ tileExp, int* __restrict__ tileM0) {
    __shared__ int h[NEXP];
    int tid = threadIdx.x;
    if (tid < NEXP) h[tid] = 0;
    __syncthreads();
    for (int i = tid; i < TOTROWS; i += 256) atomicAdd(&h[sel[i]], 1);
    __syncthreads();
    if (tid == 0) {
        int o = 0;
        for (int e = 0; e < NEXP; ++e) { cnt[e] = h[e]; off[e] = o; o += h[e]; fill[e] = 0; }
        int nt = 0;
        for (int e = 0; e < NEXP; ++e)
            for (int m0 = 0; m0 < h[e]; m0 += 128) { tileExp[nt] = e; tileM0[nt] = m0; nt++; }
        for (int i = nt; i < MAXTILES; ++i) { tileExp[i] = -1; tileM0[i] = 0; }
    }
}

// ---------------- assign: ballot-rank slots, 1 atomic/expert/block (256 atomics total) -------
__global__ __launch_bounds__(256) void assign_kernel(const int* __restrict__ sel,
                                                     const float* __restrict__ selw,
                                                     const int* __restrict__ off,
                                                     int* __restrict__ fill,
                                                     float* __restrict__ rowWgt,
                                                     int* __restrict__ tokRow) {
    __shared__ int wcnt[4][NEXP];
    __shared__ int bbase[NEXP];
    int tid = threadIdx.x, lane = tid & 63, w = tid >> 6;
    int i = blockIdx.x * 256 + tid;          // 32 blocks x 256 = 8192 entries
    int e = sel[i];
    unsigned long long below = (1ULL << lane) - 1;
    int myrank = 0;
#pragma unroll
    for (int x = 0; x < NEXP; ++x) {
        unsigned long long m = __ballot(e == x);
        if (lane == 0) wcnt[w][x] = __popcll(m);
        if (e == x) myrank = __popcll(m & below);
    }
    __syncthreads();
    if (tid < NEXP) {
        int tot = wcnt[0][tid] + wcnt[1][tid] + wcnt[2][tid] + wcnt[3][tid];
        bbase[tid] = atomicAdd(&fill[tid], tot);
    }
    __syncthreads();
    int wb = 0;
    for (int w2 = 0; w2 < w; ++w2) wb += wcnt[w2][e];
    int r = off[e] + bbase[e] + wb + myrank;
    tokRow[i] = r;
    rowWgt[r] = selw[i];
}

// ---------------- copy: x row (bf16) to both expert rows (no atomics) ----------------
__global__ __launch_bounds__(256) void copy_kernel(const int* __restrict__ tokRow,
                                                   const float* __restrict__ x,
                                                   unsigned short* __restrict__ Xg) {
    int t = blockIdx.x;
    int tid = threadIdx.x;
    int r1 = tokRow[t * 2 + 0], r2 = tokRow[t * 2 + 1];
    float4 v = ((const float4*)(x + (size_t)t * H_DIM))[tid];
    ushort4 o;
    o.x = f2b(v.x); o.y = f2b(v.y); o.z = f2b(v.z); o.w = f2b(v.w);
    ((ushort4*)(Xg + (size_t)r1 * H_DIM))[tid] = o;
    ((ushort4*)(Xg + (size_t)r2 * H_DIM))[tid] = o;
}

// ---------------- fused transpose+cvt for all 3 weight tensors ----------------
__global__ __launch_bounds__(256) void transpose_cvt_kernel(
        const float* __restrict__ w_up, const float* __restrict__ w_gate,
        const float* __restrict__ w_down,
        unsigned short* __restrict__ wTu, unsigned short* __restrict__ wTg,
        unsigned short* __restrict__ wTd) {
    __shared__ unsigned short lt[64 * 68];
    int z = blockIdx.z;
    int e = blockIdx.y;
    const float* src; unsigned short* dst; int R, C, tr, tc;
    if (z == 0)      { src = w_up;   dst = wTu; R = H_DIM; C = F_DIM; }
    else if (z == 1) { src = w_gate; dst = wTg; R = H_DIM; C = F_DIM; }
    else             { src = w_down; dst = wTd; R = F_DIM; C = H_DIM; }
    if (R == H_DIM) { tc = blockIdx.x & 31; tr = blockIdx.x >> 5; }
    else            { tc = blockIdx.x & 15; tr = blockIdx.x >> 4; }
    const float* s = src + (size_t)e * H_DIM * F_DIM;
    unsigned short* d = dst + (size_t)e * H_DIM * F_DIM;
    int r0 = tr * 64, c0 = tc * 64;
    int tid = threadIdx.x;
    int fc = tid & 15, row = tid >> 4;
#pragma unroll
    for (int i = 0; i < 4; ++i) {
        int r = row + i * 16;
        float4 v = *(const float4*)(s + (size_t)(r0 + r) * C + c0 + fc * 4);
        lt[(fc * 4 + 0) * 68 + r] = f2b(v.x);
        lt[(fc * 4 + 1) * 68 + r] = f2b(v.y);
        lt[(fc * 4 + 2) * 68 + r] = f2b(v.z);
        lt[(fc * 4 + 3) * 68 + r] = f2b(v.w);
    }
    __syncthreads();
    int ch = tid & 7, cc = tid >> 3;
#pragma unroll
    for (int i = 0; i < 2; ++i) {
        int c = cc + i * 32;
        uint2 lo = *(const uint2*)&lt[c * 68 + ch * 8];
        uint2 hi = *(const uint2*)&lt[c * 68 + ch * 8 + 4];
        uint4 o = make_uint4(lo.x, lo.y, hi.x, hi.y);
        *(uint4*)(d + (size_t)(c0 + c) * R + r0 + ch * 8) = o;
    }
}

// =============== up/gate GEMM: 128x128, BK=32, A-DIRECT from global (no A LDS), ==============
// =============== B reg-staged->LDS, 256 thr / 4 waves, 2 blocks/CU ===========================
// Per K-tile: {ds_read B frags (t) | ds_write B(t+1) from regs (compiler emits counted vmcnt
// via reg deps) | THEN issue A(t+1)-frag + B(t+2) global loads (order matters: BWRITE must
// read the regs BEFORE BLOAD overwrites them -- R6 bug) | 32 MFMA | lgkm(0); raw barrier}.
__global__ __launch_bounds__(256, 2) void gemm_upgate_kernel(
        const unsigned short* __restrict__ Xg,
        const unsigned short* __restrict__ wTu,   // [E][F][H] (k-major)
        const unsigned short* __restrict__ wTg,
        unsigned short* __restrict__ inner,       // [TOTROWS][F]
        const int* __restrict__ tileExp, const int* __restrict__ tileM0,
        const int* __restrict__ off, const int* __restrict__ cnt) {
    __shared__ __align__(16) unsigned short lbu[2][4096];   // 8KB x2 (128x32)
    __shared__ __align__(16) unsigned short lbg[2][4096];   // 32KB total
    int bt = blockIdx.y;
    int e = tileExp[bt];
    if (e < 0) return;
    int m0 = tileM0[bt];
    int r0 = off[e] + m0;
    int valid = cnt[e] - m0;
    int f0 = blockIdx.x * 128;
    const unsigned short* aB  = Xg + (size_t)r0 * H_DIM;
    const unsigned short* buW = wTu + (size_t)e * F_DIM * H_DIM + (size_t)f0 * H_DIM;
    const unsigned short* bgW = wTg + (size_t)e * F_DIM * H_DIM + (size_t)f0 * H_DIM;
    int tid = threadIdx.x;
    int lane = tid & 63, wid = tid >> 6;   // 4 waves
    int wm = wid >> 1, wn = wid & 1;       // 2M x 2N -> 64x64 per wave (dual U+G acc)
    int l16 = lane & 15, quad = lane >> 4;

    // B staging map: 512 chunks/tile; thread owns chunks tid, tid+256
    int rB0 = tid >> 2, rB1 = rB0 + 64;
    int s0 = rB0 * H_DIM + (tid & 3) * 8;
    int s1 = rB1 * H_DIM + (tid & 3) * 8;
    int d0 = rB0 * 32 + (((tid & 3) ^ (rB0 & 3)) << 3);
    int d1 = rB1 * 32 + (((tid & 3) ^ (rB1 & 3)) << 3);

    // B fragment LDS indices; A fragment GLOBAL offsets (elements)
    int bIdx[4], aOff[4];
#pragma unroll
    for (int j = 0; j < 4; ++j) {
        int lr = wn * 64 + j * 16 + l16;
        bIdx[j] = lr * 32 + ((quad ^ (lr & 3)) << 3);
    }
#pragma unroll
    for (int i = 0; i < 4; ++i) {
        int lr = wm * 64 + i * 16 + l16;
        aOff[i] = lr * H_DIM + quad * 8;   // tail rows overread into ws pad (rows masked at C-write)
    }

    f32x4 accU[4][4], accG[4][4];
#pragma unroll
    for (int i = 0; i < 4; ++i)
#pragma unroll
        for (int j = 0; j < 4; ++j) { accU[i][j] = (f32x4)0.f; accG[i][j] = (f32x4)0.f; }

    bf16x8 afA[4], afB[4];          // ping/pong A fragments (static indices only)
    uint4 vu0, vu1, vg0, vg1;       // B staging regs (one tile)

#define UPG_BLOAD(K0) do {                                       \
    vu0 = *(const uint4*)(buW + s0 + (K0));                      \
    vu1 = *(const uint4*)(buW + s1 + (K0));                      \
    vg0 = *(const uint4*)(bgW + s0 + (K0));                      \
    vg1 = *(const uint4*)(bgW + s1 + (K0));                      \
} while (0)
#define UPG_BWRITE(NB) do {                                      \
    *(uint4*)&lbu[NB][d0] = vu0;  *(uint4*)&lbu[NB][d1] = vu1;   \
    *(uint4*)&lbg[NB][d0] = vg0;  *(uint4*)&lbg[NB][d1] = vg1;   \
} while (0)
#define UPG_ALOAD(AF, K0) do {                                   \
    _Pragma("unroll") for (int i_ = 0; i_ < 4; ++i_)             \
        AF[i_] = *(const bf16x8*)(aB + aOff[i_] + (K0));         \
} while (0)

    // prologue: A(0)->afA; B(0)->regs->lds[0]; B(1)->regs
    UPG_ALOAD(afA, 0);
    UPG_BLOAD(0);
    UPG_BWRITE(0);
    UPG_BLOAD(32);
    asm volatile("s_waitcnt lgkmcnt(0)" ::: "memory");
    __builtin_amdgcn_s_barrier();
    __builtin_amdgcn_sched_barrier(0);

// step T: compute tile T from lds[CUR]+AFC; publish B(T+1) regs->lds[NXT] FIRST,
// then prefetch A(T+1)->AFN and B(T+2)->regs (overwrites staging regs only after
// the ds_write consumed them).
#define UPG_STEP(T, CUR, NXT, AFC, AFN) do {                                      \
    bf16x8 bu_[4], bg_[4];                                                        \
    _Pragma("unroll") for (int j_ = 0; j_ < 4; ++j_) {                            \
        bu_[j_] = *(const bf16x8*)&lbu[CUR][bIdx[j_]];                            \
        bg_[j_] = *(const bf16x8*)&lbg[CUR][bIdx[j_]];                            \
    }                                                                             \
    if ((T) < 31) UPG_BWRITE(NXT);                                                \
    if ((T) < 31) UPG_ALOAD(AFN, ((T) + 1) * 32);                                 \
    if ((T) < 30) UPG_BLOAD(((T) + 2) * 32);                                      \
    __builtin_amdgcn_s_setprio(1);                                                \
    _Pragma("unroll") for (int i_ = 0; i_ < 4; ++i_)                              \
        _Pragma("unroll") for (int j_ = 0; j_ < 4; ++j_) {                        \
            accU[i_][j_] = __builtin_amdgcn_mfma_f32_16x16x32_bf16(AFC[i_], bu_[j_], accU[i_][j_], 0, 0, 0); \
            accG[i_][j_] = __builtin_amdgcn_mfma_f32_16x16x32_bf16(AFC[i_], bg_[j_], accG[i_][j_], 0, 0, 0); \
        }                                                                         \
    __builtin_amdgcn_s_setprio(0);                                                \
    asm volatile("s_waitcnt lgkmcnt(0)" ::: "memory");                            \
    __builtin_amdgcn_s_barrier();                                                 \
    __builtin_amdgcn_sched_barrier(0);                                            \
} while (0)

    for (int t = 0; t < 32; t += 2) {     // K = 1024/32 = 32 tiles
        UPG_STEP(t,     0, 1, afA, afB);
        UPG_STEP(t + 1, 1, 0, afB, afA);
    }
#undef UPG_STEP
#undef UPG_ALOAD
#undef UPG_BLOAD
#undef UPG_BWRITE

#pragma unroll
    for (int i = 0; i < 4; ++i) {
#pragma unroll
        for (int rr = 0; rr < 4; ++rr) {
            int ml = wm * 64 + i * 16 + quad * 4 + rr;
            if (ml >= valid) continue;
            size_t base = (size_t)(r0 + ml) * F_DIM + f0;
#pragma unroll
            for (int j = 0; j < 4; ++j) {
                float u = accU[i][j][rr];
                float g = accG[i][j][rr];
                float v = u * __builtin_amdgcn_rcpf(1.f + __expf(-u)) * g;   // silu(up)*gate
                inner[base + wn * 64 + j * 16 + l16] = f2b(v);
            }
        }
    }
}

// =============== down GEMM: 128x128, BK=32, REG-staged, 256 thr / 4 waves, 3 blocks/CU =======
// (R5-proven order: ds_read -> WRITE(nxt) -> LOAD(t+2) -> MFMA)
__global__ __launch_bounds__(256, 3) void gemm_down_kernel(
        const unsigned short* __restrict__ inner,  // [TOTROWS][F]
        const unsigned short* __restrict__ wTd,    // [E][H][F] (k-major)
        float* __restrict__ part,                  // [TOTROWS][H]
        const int* __restrict__ tileExp, const int* __restrict__ tileM0,
        const int* __restrict__ off, const int* __restrict__ cnt,
        const float* __restrict__ rowWgt) {
    __shared__ __align__(16) unsigned short la[2][4096];   // 8KB x2 (128x32)
    __shared__ __align__(16) unsigned short lb[2][4096];   // 32KB total -> 3 blocks/CU
    int bt = blockIdx.y;
    int e = tileExp[bt];
    if (e < 0) return;
    int m0 = tileM0[bt];
    int r0 = off[e] + m0;
    int valid = cnt[e] - m0;
    int h0 = blockIdx.x * 128;
    const unsigned short* aB = inner + (size_t)r0 * F_DIM;
    const unsigned short* bp = wTd + (size_t)e * H_DIM * F_DIM + (size_t)h0 * F_DIM;
    int tid = threadIdx.x;
    int lane = tid & 63, wid = tid >> 6;   // 4 waves
    int wm = wid >> 1, wn = wid & 1;       // 2M x 2N -> 64x64 per wave
    int l16 = lane & 15, quad = lane >> 4;

    int rA0 = tid >> 2, rA1 = rA0 + 64;
    int s0 = rA0 * F_DIM + (tid & 3) * 8;
    int s1 = rA1 * F_DIM + (tid & 3) * 8;
    int d0 = rA0 * 32 + (((tid & 3) ^ (rA0 & 3)) << 3);
    int d1 = rA1 * 32 + (((tid & 3) ^ (rA1 & 3)) << 3);

    int aIdx[4], bIdx[4];
#pragma unroll
    for (int i = 0; i < 4; ++i) {
        int lr = wm * 64 + i * 16 + l16;
        aIdx[i] = lr * 32 + ((quad ^ (lr & 3)) << 3);
    }
#pragma unroll
    for (int j = 0; j < 4; ++j) {
        int lr = wn * 64 + j * 16 + l16;
        bIdx[j] = lr * 32 + ((quad ^ (lr & 3)) << 3);
    }

    f32x4 acc[4][4];
#pragma unroll
    for (int i = 0; i < 4; ++i)
#pragma unroll
        for (int j = 0; j < 4; ++j) acc[i][j] = (f32x4)0.f;

    uint4 va0, va1, vb0, vb1;

#define DWN_LOAD(K0) do {                                        \
    va0 = *(const uint4*)(aB + s0 + (K0));                       \
    va1 = *(const uint4*)(aB + s1 + (K0));                       \
    vb0 = *(const uint4*)(bp + s0 + (K0));                       \
    vb1 = *(const uint4*)(bp + s1 + (K0));                       \
} while (0)
#define DWN_WRITE(NB) do {                                       \
    *(uint4*)&la[NB][d0] = va0;  *(uint4*)&la[NB][d1] = va1;     \
    *(uint4*)&lb[NB][d0] = vb0;  *(uint4*)&lb[NB][d1] = vb1;     \
} while (0)

    DWN_LOAD(0);
    DWN_WRITE(0);
    DWN_LOAD(32);
    asm volatile("s_waitcnt lgkmcnt(0)" ::: "memory");
    __builtin_amdgcn_s_barrier();
    __builtin_amdgcn_sched_barrier(0);

    for (int t = 0; t < 64; ++t) {        // K = 2048/32 = 64 tiles
        int cur = t & 1, nxt = cur ^ 1;
        const unsigned short* lac = la[cur];
        const unsigned short* lbc = lb[cur];
        bf16x8 af[4], bw[4];
#pragma unroll
        for (int i = 0; i < 4; ++i) af[i] = *(const bf16x8*)(lac + aIdx[i]);
#pragma unroll
        for (int j = 0; j < 4; ++j) bw[j] = *(const bf16x8*)(lbc + bIdx[j]);
        if (t < 63) DWN_WRITE(nxt);
        if (t < 62) DWN_LOAD((t + 2) * 32);
        __builtin_amdgcn_s_setprio(1);
#pragma unroll
        for (int i = 0; i < 4; ++i)
#pragma unroll
            for (int j = 0; j < 4; ++j)
                acc[i][j] = __builtin_amdgcn_mfma_f32_16x16x32_bf16(af[i], bw[j], acc[i][j], 0, 0, 0);
        __builtin_amdgcn_s_setprio(0);
        asm volatile("s_waitcnt lgkmcnt(0)" ::: "memory");
        __builtin_amdgcn_s_barrier();
        __builtin_amdgcn_sched_barrier(0);
    }
#undef DWN_LOAD
#undef DWN_WRITE

#pragma unroll
    for (int i = 0; i < 4; ++i) {
#pragma unroll
        for (int rr = 0; rr < 4; ++rr) {
            int ml = wm * 64 + i * 16 + quad * 4 + rr;
            if (ml >= valid) continue;
            int gr = r0 + ml;
            float w = rowWgt[gr];
            float* orow = part + (size_t)gr * H_DIM + h0;
#pragma unroll
            for (int j = 0; j < 4; ++j)
                orow[wn * 64 + j * 16 + l16] = w * acc[i][j][rr];
        }
    }
}

// ---------------- combine: out[t] = part[r1] + part[r2] ----------------
__global__ __launch_bounds__(256) void combine_kernel(const float* __restrict__ part,
                                                      const int* __restrict__ tokRow,
                                                      float* __restrict__ out) {
    int t = blockIdx.x;
    int r1 = tokRow[t * 2 + 0], r2 = tokRow[t * 2 + 1];
    int i = threadIdx.x;
    float4 a = ((const float4*)(part + (size_t)r1 * H_DIM))[i];
    float4 b = ((const float4*)(part + (size_t)r2 * H_DIM))[i];
    float4 o;
    o.x = a.x + b.x; o.y = a.y + b.y; o.z = a.z + b.z; o.w = a.w + b.w;
    ((float4*)(out + (size_t)t * H_DIM))[i] = o;
}

extern "C" void kernel_launch(void* const* d_in, const int* in_sizes, int n_in,
                              void* d_out, int out_size, void* d_ws, size_t ws_size,
                              hipStream_t stream) {
    const float* x      = (const float*)d_in[0];
    const float* gw     = (const float*)d_in[1];
    const float* w_up   = (const float*)d_in[2];
    const float* w_gate = (const float*)d_in[3];
    const float* w_down = (const float*)d_in[4];
    float* out = (float*)d_out;

    char* ws = (char*)d_ws;
    size_t o = 0;
    unsigned short* wTu = (unsigned short*)(ws + o); o += (size_t)NEXP * F_DIM * H_DIM * 2;
    unsigned short* wTg = (unsigned short*)(ws + o); o += (size_t)NEXP * F_DIM * H_DIM * 2;
    unsigned short* wTd = (unsigned short*)(ws + o); o += (size_t)NEXP * H_DIM * F_DIM * 2;
    unsigned short* Xg  = (unsigned short*)(ws + o); o += (size_t)TOTROWS * H_DIM * 2;
    unsigned short* inner = (unsigned short*)(ws + o); o += (size_t)TOTROWS * F_DIM * 2;
    o += 2 * 1024 * 1024;  // pad: tail-row overreads stay in ws
    float* rowWgt = (float*)(ws + o); o += TOTROWS * 4;
    int*   tokRow = (int*)(ws + o);   o += T_TOK * 2 * 4;
    int*   sel    = (int*)(ws + o);   o += T_TOK * 2 * 4;
    float* selw   = (float*)(ws + o); o += T_TOK * 2 * 4;
    int*   cnt    = (int*)(ws + o);   o += 8 * 4;
    int*   fill   = (int*)(ws + o);   o += 8 * 4;
    int*   off_   = (int*)(ws + o);   o += 8 * 4;
    int*   tileExp = (int*)(ws + o);  o += MAXTILES * 4;
    int*   tileM0  = (int*)(ws + o);  o += MAXTILES * 4;
    // part[TOTROWS][H] fp32 aliases wTu+wTg (dead after gemm_upgate; stream-serial)
    float* part = (float*)wTu;

    router_kernel<<<T_TOK / 4, 256, 0, stream>>>(x, gw, sel, selw);
    scan_kernel<<<1, 256, 0, stream>>>(sel, cnt, off_, fill, tileExp, tileM0);
    assign_kernel<<<TOTROWS / 256, 256, 0, stream>>>(sel, selw, off_, fill, rowWgt, tokRow);
    copy_kernel<<<T_TOK, 256, 0, stream>>>(tokRow, x, Xg);
    transpose_cvt_kernel<<<dim3(512, NEXP, 3), 256, 0, stream>>>(w_up, w_gate, w_down, wTu, wTg, wTd);
    gemm_upgate_kernel<<<dim3(F_DIM / 128, 72), 256, 0, stream>>>(Xg, wTu, wTg, inner, tileExp, tileM0, off_, cnt);
    gemm_down_kernel<<<dim3(H_DIM / 128, 72), 256, 0, stream>>>(inner, wTd, part, tileExp, tileM0, off_, cnt, rowWgt);
    combine_kernel<<<T_TOK, 256, 0, stream>>>(part, tokRow, out);
}